// Round 2
// baseline (1081.796 us; speedup 1.0000x reference)
//
#include <hip/hip_runtime.h>
#include <math.h>

// Problem constants (from reference)
constexpr int Bc   = 8;
constexpr int Nn   = 4500;
constexpr int Ec   = 72000;
constexpr int D    = 128;          // IN_DIM == OUT_DIM == 128
constexpr int T    = Bc * Nn;      // 36000 total nodes
constexpr int TE   = Bc * Ec;      // 576000 total edges
constexpr float EPS = 1e-5f;

// ---------------------------------------------------------------------------
// GEMM: h[n][o] = sum_k x[n][k] * W[o][k] + b[o]
// Block: 256 threads, 64 nodes. W fully staged in LDS (64KB), x tile padded
// pitch 132 floats (33 float4) for bank spread. Thread: 2 nodes x 16 outputs.
// ---------------------------------------------------------------------------
__global__ __launch_bounds__(256) void gemm_kernel(
    const float* __restrict__ x, const float* __restrict__ W,
    const float* __restrict__ bias, float* __restrict__ h) {
  __shared__ float4 Wl[128 * 32];   // [o][k4], pitch 32 float4 (64 KB)
  __shared__ float4 Xl[64 * 33];    // [n][k4], pitch 33 float4 (132 floats)

  const int tid = threadIdx.x;
  const int nb  = blockIdx.x * 64;

  const float4* W4 = (const float4*)W;
#pragma unroll
  for (int i = 0; i < 16; ++i) Wl[tid + i * 256] = W4[tid + i * 256];

  const float4* X4 = (const float4*)x;
#pragma unroll
  for (int i = 0; i < 8; ++i) {
    int flat = tid + i * 256;            // [0, 2048)
    int row  = flat >> 5;
    int c4   = flat & 31;
    int node = nb + row;
    float4 v = make_float4(0.f, 0.f, 0.f, 0.f);
    if (node < T) v = X4[node * 32 + c4];
    Xl[row * 33 + c4] = v;
  }
  __syncthreads();

  const int nl = tid & 31;       // node pair base (nl, nl+32)
  const int og = tid >> 5;       // output group 0..7 (16 outputs each)
  const int o0 = og * 16;

  float accA[16], accB[16];
#pragma unroll
  for (int j = 0; j < 16; ++j) { accA[j] = 0.f; accB[j] = 0.f; }

#pragma unroll 2
  for (int k4 = 0; k4 < 32; ++k4) {
    float4 xa = Xl[nl * 33 + k4];
    float4 xb = Xl[(nl + 32) * 33 + k4];
#pragma unroll
    for (int j = 0; j < 16; ++j) {
      float4 w = Wl[(o0 + j) * 32 + k4];
      accA[j] += xa.x * w.x + xa.y * w.y + xa.z * w.z + xa.w * w.w;
      accB[j] += xb.x * w.x + xb.y * w.y + xb.z * w.z + xb.w * w.w;
    }
  }

  const int nodeA = nb + nl;
  const int nodeB = nb + nl + 32;
  float4* H4 = (float4*)h;
  const float4* B4 = (const float4*)bias;
#pragma unroll
  for (int j4 = 0; j4 < 4; ++j4) {
    float4 bv = B4[og * 4 + j4];
    float4 ra, rb;
    ra.x = accA[j4 * 4 + 0] + bv.x; ra.y = accA[j4 * 4 + 1] + bv.y;
    ra.z = accA[j4 * 4 + 2] + bv.z; ra.w = accA[j4 * 4 + 3] + bv.w;
    rb.x = accB[j4 * 4 + 0] + bv.x; rb.y = accB[j4 * 4 + 1] + bv.y;
    rb.z = accB[j4 * 4 + 2] + bv.z; rb.w = accB[j4 * 4 + 3] + bv.w;
    if (nodeA < T) H4[nodeA * 32 + og * 4 + j4] = ra;
    if (nodeB < T) H4[nodeB * 32 + og * 4 + j4] = rb;
  }
}

// ---------------------------------------------------------------------------
// Degree: deg[tgt] += edge_mask[e]  (atomic, 576K edges). edge_index is int32.
// Layout: ei[b][0][e] = src, ei[b][1][e] = tgt, flattened [B,2,E].
// ---------------------------------------------------------------------------
__global__ __launch_bounds__(256) void deg_kernel(
    const int* __restrict__ ei, const float* __restrict__ em,
    float* __restrict__ deg) {
  int e = blockIdx.x * 256 + threadIdx.x;
  if (e >= TE) return;
  int b  = e / Ec;
  int el = e - b * Ec;
  float ew = em[e];
  if (ew != 0.f) {
    int t = ei[b * 2 * Ec + Ec + el];
    if ((unsigned)t < (unsigned)Nn)           // defensive: never fault
      atomicAdd(&deg[t + b * Nn], ew);
  }
}

// dinv[i] = (deg[i] + 1)^{-1/2}, in place over deg
__global__ __launch_bounds__(256) void dinv_kernel(float* __restrict__ deg) {
  int i = blockIdx.x * 256 + threadIdx.x;
  if (i >= T) return;
  deg[i] = 1.0f / sqrtf(deg[i] + 1.0f);
}

// ---------------------------------------------------------------------------
// Scatter: agg[tgt] += h[src] * (dinv[src]*dinv[tgt]*ew)
// One thread per (edge, quarter-row float4): 18.4M threads, 4 f32 atomics each
// ---------------------------------------------------------------------------
__global__ __launch_bounds__(256) void scatter_kernel(
    const int* __restrict__ ei, const float* __restrict__ em,
    const float* __restrict__ dinv, const float* __restrict__ h,
    float* __restrict__ agg) {
  int gid = blockIdx.x * 256 + threadIdx.x;   // [0, TE*32)
  int e = gid >> 5;
  int q = gid & 31;
  int b  = e / Ec;
  int el = e - b * Ec;
  float ew = em[e];
  if (ew == 0.f) return;
  const int* eb = ei + b * 2 * Ec;
  int s0 = eb[el];
  int t0 = eb[Ec + el];
  if ((unsigned)s0 >= (unsigned)Nn || (unsigned)t0 >= (unsigned)Nn) return;
  int s = s0 + b * Nn;
  int t = t0 + b * Nn;
  float coef = dinv[s] * dinv[t] * ew;
  float4 v = ((const float4*)h)[s * 32 + q];
  float* ap = agg + (size_t)t * D + q * 4;
  atomicAdd(ap + 0, v.x * coef);
  atomicAdd(ap + 1, v.y * coef);
  atomicAdd(ap + 2, v.z * coef);
  atomicAdd(ap + 3, v.w * coef);
}

// ---------------------------------------------------------------------------
// LayerNorm + ReLU + mask. One 64-lane wave per node row, float2 per lane.
// pre = h*(1+dinv) + agg ; LN ; relu ; *mask — overwrites h (d_out) in place.
// ---------------------------------------------------------------------------
__global__ __launch_bounds__(256) void ln_kernel(
    float* __restrict__ h, const float* __restrict__ agg,
    const float* __restrict__ dinv, const float* __restrict__ gamma,
    const float* __restrict__ beta, const float* __restrict__ mask) {
  int node = blockIdx.x * 4 + (threadIdx.x >> 6);
  int lane = threadIdx.x & 63;
  if (node >= T) return;

  float2 hv = ((const float2*)h)[node * 64 + lane];
  float2 av = ((const float2*)agg)[node * 64 + lane];
  float di  = dinv[node];
  float2 t;
  t.x = hv.x * (1.f + di) + av.x;
  t.y = hv.y * (1.f + di) + av.y;

  float s  = t.x + t.y;
  float ss = t.x * t.x + t.y * t.y;
#pragma unroll
  for (int o = 32; o > 0; o >>= 1) {
    s  += __shfl_xor(s, o);
    ss += __shfl_xor(ss, o);
  }
  float mu  = s * (1.0f / 128.0f);
  float var = ss * (1.0f / 128.0f) - mu * mu;
  float rs  = 1.0f / sqrtf(var + EPS);
  float m   = mask[node];

  float2 g  = ((const float2*)gamma)[lane];
  float2 bb = ((const float2*)beta)[lane];
  float y0 = (t.x - mu) * rs * g.x + bb.x;
  float y1 = (t.y - mu) * rs * g.y + bb.y;
  y0 = fmaxf(y0, 0.f) * m;
  y1 = fmaxf(y1, 0.f) * m;
  float2 r; r.x = y0; r.y = y1;
  ((float2*)h)[node * 64 + lane] = r;
}

// ---------------------------------------------------------------------------
extern "C" void kernel_launch(void* const* d_in, const int* in_sizes, int n_in,
                              void* d_out, int out_size, void* d_ws, size_t ws_size,
                              hipStream_t stream) {
  const float* x     = (const float*)d_in[0];
  const int*   ei    = (const int*)d_in[1];     // int32 on device (harness)
  const float* nmask = (const float*)d_in[2];
  const float* emask = (const float*)d_in[3];
  const float* W     = (const float*)d_in[4];
  const float* bias  = (const float*)d_in[5];
  const float* gamma = (const float*)d_in[6];
  const float* beta  = (const float*)d_in[7];
  float* out = (float*)d_out;

  char*  ws  = (char*)d_ws;
  float* deg = (float*)ws;                       // T floats (doubles as dinv)
  float* agg = (float*)(ws + 147456);            // T*128 floats (18.43 MB)

  // ws is NOT re-poisoned between replays — zero our accumulators every call.
  hipMemsetAsync(deg, 0, (size_t)T * sizeof(float), stream);
  hipMemsetAsync(agg, 0, (size_t)T * D * sizeof(float), stream);

  // GEMM writes h into d_out (used as scratch; ln_kernel overwrites fully).
  gemm_kernel<<<(T + 63) / 64, 256, 0, stream>>>(x, W, bias, out);
  deg_kernel<<<(TE + 255) / 256, 256, 0, stream>>>(ei, emask, deg);
  dinv_kernel<<<(T + 255) / 256, 256, 0, stream>>>(deg);
  scatter_kernel<<<(TE * 32) / 256, 256, 0, stream>>>(ei, emask, deg, out, agg);
  ln_kernel<<<T / 4, 256, 0, stream>>>(out, agg, deg, gamma, beta, nmask);
}

// Round 3
// 302.098 us; speedup vs baseline: 3.5809x; 3.5809x over previous
//
#include <hip/hip_runtime.h>
#include <math.h>

// Problem constants (from reference)
constexpr int Bc   = 8;
constexpr int Nn   = 4500;
constexpr int Ec   = 72000;
constexpr int D    = 128;          // IN_DIM == OUT_DIM == 128
constexpr int T    = Bc * Nn;      // 36000 total nodes
constexpr int TE   = Bc * Ec;      // 576000 total edges
constexpr float EPS = 1e-5f;

// Workspace layout (bytes)
constexpr size_t WS_DEG    = 0;          // T f32   (deg -> dinv in place)
constexpr size_t WS_CNT    = 147456;     // T i32   (edges per target)
constexpr size_t WS_ROWPTR = 294912;     // T+1 i32
constexpr size_t WS_CUR    = 442368;     // T i32   (fill cursors)
constexpr size_t WS_ESRC   = 589824;     // TE i32  (src, sorted by tgt)
constexpr size_t WS_ECOEF  = 2893824;    // TE f32  (coef, sorted by tgt)
constexpr size_t WS_H      = 5197824;    // T*D f32 (GEMM output h)

// ---------------------------------------------------------------------------
// GEMM: h[n][o] = sum_k x[n][k] * W[o][k] + b[o]
// Block: 256 threads, 64 nodes. W fully staged in LDS (64KB), x tile padded
// pitch 132 floats (33 float4). Thread: 2 nodes x 16 outputs.
// ---------------------------------------------------------------------------
__global__ __launch_bounds__(256) void gemm_kernel(
    const float* __restrict__ x, const float* __restrict__ W,
    const float* __restrict__ bias, float* __restrict__ h) {
  __shared__ float4 Wl[128 * 32];   // [o][k4]
  __shared__ float4 Xl[64 * 33];    // [n][k4], padded

  const int tid = threadIdx.x;
  const int nb  = blockIdx.x * 64;

  const float4* W4 = (const float4*)W;
#pragma unroll
  for (int i = 0; i < 16; ++i) Wl[tid + i * 256] = W4[tid + i * 256];

  const float4* X4 = (const float4*)x;
#pragma unroll
  for (int i = 0; i < 8; ++i) {
    int flat = tid + i * 256;
    int row  = flat >> 5;
    int c4   = flat & 31;
    int node = nb + row;
    float4 v = make_float4(0.f, 0.f, 0.f, 0.f);
    if (node < T) v = X4[node * 32 + c4];
    Xl[row * 33 + c4] = v;
  }
  __syncthreads();

  const int nl = tid & 31;
  const int og = tid >> 5;
  const int o0 = og * 16;

  float accA[16], accB[16];
#pragma unroll
  for (int j = 0; j < 16; ++j) { accA[j] = 0.f; accB[j] = 0.f; }

#pragma unroll 2
  for (int k4 = 0; k4 < 32; ++k4) {
    float4 xa = Xl[nl * 33 + k4];
    float4 xb = Xl[(nl + 32) * 33 + k4];
#pragma unroll
    for (int j = 0; j < 16; ++j) {
      float4 w = Wl[(o0 + j) * 32 + k4];
      accA[j] += xa.x * w.x + xa.y * w.y + xa.z * w.z + xa.w * w.w;
      accB[j] += xb.x * w.x + xb.y * w.y + xb.z * w.z + xb.w * w.w;
    }
  }

  const int nodeA = nb + nl;
  const int nodeB = nb + nl + 32;
  float4* H4 = (float4*)h;
  const float4* B4 = (const float4*)bias;
#pragma unroll
  for (int j4 = 0; j4 < 4; ++j4) {
    float4 bv = B4[og * 4 + j4];
    float4 ra, rb;
    ra.x = accA[j4 * 4 + 0] + bv.x; ra.y = accA[j4 * 4 + 1] + bv.y;
    ra.z = accA[j4 * 4 + 2] + bv.z; ra.w = accA[j4 * 4 + 3] + bv.w;
    rb.x = accB[j4 * 4 + 0] + bv.x; rb.y = accB[j4 * 4 + 1] + bv.y;
    rb.z = accB[j4 * 4 + 2] + bv.z; rb.w = accB[j4 * 4 + 3] + bv.w;
    if (nodeA < T) H4[nodeA * 32 + og * 4 + j4] = ra;
    if (nodeB < T) H4[nodeB * 32 + og * 4 + j4] = rb;
  }
}

// ---------------------------------------------------------------------------
// Edge pass 1: cnt[tgt]++ (all edges) and deg[tgt] += ew (masked).
// edge_index is int32, layout [B,2,E]: ei[b][0][e]=src, ei[b][1][e]=tgt.
// ---------------------------------------------------------------------------
__global__ __launch_bounds__(256) void deg_cnt_kernel(
    const int* __restrict__ ei, const float* __restrict__ em,
    float* __restrict__ deg, int* __restrict__ cnt) {
  int e = blockIdx.x * 256 + threadIdx.x;
  if (e >= TE) return;
  int b  = e / Ec;
  int el = e - b * Ec;
  int t = ei[b * 2 * Ec + Ec + el];
  if ((unsigned)t >= (unsigned)Nn) return;   // defensive
  int tg = t + b * Nn;
  atomicAdd(&cnt[tg], 1);
  float ew = em[e];
  if (ew != 0.f) atomicAdd(&deg[tg], ew);
}

// ---------------------------------------------------------------------------
// Single-block scan: rowptr = exclusive_scan(cnt), rowptr[T] = total.
// Also folds dinv: deg[i] = 1/sqrt(deg[i]+1).
// 1024 threads, SEG = 36 elements each.
// ---------------------------------------------------------------------------
__global__ __launch_bounds__(1024) void scan_dinv_kernel(
    const int* __restrict__ cnt, int* __restrict__ rowptr,
    float* __restrict__ deg) {
  constexpr int SEG = 36;   // 1024*36 = 36864 >= T
  __shared__ int sh[1024];
  const int i = threadIdx.x;
  const int base = i * SEG;

  int s = 0;
#pragma unroll
  for (int j = 0; j < SEG; ++j) {
    int idx = base + j;
    if (idx < T) s += cnt[idx];
  }
  sh[i] = s;
  __syncthreads();
#pragma unroll
  for (int off = 1; off < 1024; off <<= 1) {
    int v = (i >= off) ? sh[i - off] : 0;
    __syncthreads();
    sh[i] += v;
    __syncthreads();
  }
  int running = sh[i] - s;   // exclusive prefix
#pragma unroll
  for (int j = 0; j < SEG; ++j) {
    int idx = base + j;
    if (idx < T) {
      rowptr[idx] = running;
      running += cnt[idx];
      deg[idx] = 1.0f / sqrtf(deg[idx] + 1.0f);
    }
  }
  if (i == 0) rowptr[T] = sh[1023];
}

// ---------------------------------------------------------------------------
// Edge pass 2: place each edge into CSR slot; store src and coef.
// ---------------------------------------------------------------------------
__global__ __launch_bounds__(256) void fill_kernel(
    const int* __restrict__ ei, const float* __restrict__ em,
    const float* __restrict__ dinv, const int* __restrict__ rowptr,
    int* __restrict__ cur, int* __restrict__ esrc,
    float* __restrict__ ecoef) {
  int e = blockIdx.x * 256 + threadIdx.x;
  if (e >= TE) return;
  int b  = e / Ec;
  int el = e - b * Ec;
  const int* eb = ei + b * 2 * Ec;
  int s0 = eb[el];
  int t0 = eb[Ec + el];
  if ((unsigned)s0 >= (unsigned)Nn || (unsigned)t0 >= (unsigned)Nn) return;
  int sg = s0 + b * Nn;
  int tg = t0 + b * Nn;
  float ew   = em[e];
  float coef = dinv[sg] * dinv[tg] * ew;
  int pos = rowptr[tg] + atomicAdd(&cur[tg], 1);
  esrc[pos]  = sg;
  ecoef[pos] = coef;
}

// ---------------------------------------------------------------------------
// Fused gather + residual + LayerNorm + ReLU + mask.
// One 64-lane wave per target node; float2 per lane. No feature atomics.
// ---------------------------------------------------------------------------
__global__ __launch_bounds__(256) void gather_ln_kernel(
    const float* __restrict__ h, const int* __restrict__ rowptr,
    const int* __restrict__ esrc, const float* __restrict__ ecoef,
    const float* __restrict__ dinv, const float* __restrict__ gamma,
    const float* __restrict__ beta, const float* __restrict__ mask,
    float* __restrict__ out) {
  const int node = blockIdx.x * 4 + (threadIdx.x >> 6);
  const int lane = threadIdx.x & 63;
  if (node >= T) return;

  const float2* h2 = (const float2*)h;
  const float di = dinv[node];
  float2 acc = h2[(size_t)node * 64 + lane];
  acc.x *= (1.f + di);
  acc.y *= (1.f + di);

  const int r0 = rowptr[node];
  const int r1 = rowptr[node + 1];
  int i = r0;
  for (; i + 3 < r1; i += 4) {
    int   s0 = esrc[i],     s1 = esrc[i + 1];
    int   s2 = esrc[i + 2], s3 = esrc[i + 3];
    float c0 = ecoef[i],     c1 = ecoef[i + 1];
    float c2 = ecoef[i + 2], c3 = ecoef[i + 3];
    float2 v0 = h2[(size_t)s0 * 64 + lane];
    float2 v1 = h2[(size_t)s1 * 64 + lane];
    float2 v2 = h2[(size_t)s2 * 64 + lane];
    float2 v3 = h2[(size_t)s3 * 64 + lane];
    acc.x += v0.x * c0 + v1.x * c1 + v2.x * c2 + v3.x * c3;
    acc.y += v0.y * c0 + v1.y * c1 + v2.y * c2 + v3.y * c3;
  }
  for (; i < r1; ++i) {
    int   s = esrc[i];
    float c = ecoef[i];
    float2 v = h2[(size_t)s * 64 + lane];
    acc.x += v.x * c;
    acc.y += v.y * c;
  }

  // LayerNorm over 128 features (wave reduction)
  float su = acc.x + acc.y;
  float ss = acc.x * acc.x + acc.y * acc.y;
#pragma unroll
  for (int o = 32; o > 0; o >>= 1) {
    su += __shfl_xor(su, o);
    ss += __shfl_xor(ss, o);
  }
  float mu  = su * (1.0f / 128.0f);
  float var = ss * (1.0f / 128.0f) - mu * mu;
  float rs  = 1.0f / sqrtf(var + EPS);
  float m   = mask[node];

  float2 g  = ((const float2*)gamma)[lane];
  float2 bb = ((const float2*)beta)[lane];
  float y0 = (acc.x - mu) * rs * g.x + bb.x;
  float y1 = (acc.y - mu) * rs * g.y + bb.y;
  y0 = fmaxf(y0, 0.f) * m;
  y1 = fmaxf(y1, 0.f) * m;
  float2 r; r.x = y0; r.y = y1;
  ((float2*)out)[(size_t)node * 64 + lane] = r;
}

// ---------------------------------------------------------------------------
extern "C" void kernel_launch(void* const* d_in, const int* in_sizes, int n_in,
                              void* d_out, int out_size, void* d_ws, size_t ws_size,
                              hipStream_t stream) {
  const float* x     = (const float*)d_in[0];
  const int*   ei    = (const int*)d_in[1];     // int32 on device
  const float* nmask = (const float*)d_in[2];
  const float* emask = (const float*)d_in[3];
  const float* W     = (const float*)d_in[4];
  const float* bias  = (const float*)d_in[5];
  const float* gamma = (const float*)d_in[6];
  const float* beta  = (const float*)d_in[7];
  float* out = (float*)d_out;

  char*  ws     = (char*)d_ws;
  float* deg    = (float*)(ws + WS_DEG);
  int*   cnt    = (int*)  (ws + WS_CNT);
  int*   rowptr = (int*)  (ws + WS_ROWPTR);
  int*   cur    = (int*)  (ws + WS_CUR);
  int*   esrc   = (int*)  (ws + WS_ESRC);
  float* ecoef  = (float*)(ws + WS_ECOEF);
  float* h      = (float*)(ws + WS_H);

  // ws is never re-poisoned between replays — zero accumulators every call.
  hipMemsetAsync(deg, 0, (size_t)T * sizeof(float), stream);
  hipMemsetAsync(cnt, 0, (size_t)T * sizeof(int), stream);
  hipMemsetAsync(cur, 0, (size_t)T * sizeof(int), stream);

  gemm_kernel<<<(T + 63) / 64, 256, 0, stream>>>(x, W, bias, h);
  deg_cnt_kernel<<<(TE + 255) / 256, 256, 0, stream>>>(ei, emask, deg, cnt);
  scan_dinv_kernel<<<1, 1024, 0, stream>>>(cnt, rowptr, deg);
  fill_kernel<<<(TE + 255) / 256, 256, 0, stream>>>(ei, emask, deg, rowptr,
                                                    cur, esrc, ecoef);
  gather_ln_kernel<<<T / 4, 256, 0, stream>>>(h, rowptr, esrc, ecoef, deg,
                                              gamma, beta, nmask, out);
}

// Round 4
// 192.613 us; speedup vs baseline: 5.6164x; 1.5684x over previous
//
#include <hip/hip_runtime.h>
#include <math.h>

// Problem constants (from reference)
constexpr int Bc   = 8;
constexpr int Nn   = 4500;
constexpr int Ec   = 72000;
constexpr int D    = 128;          // IN_DIM == OUT_DIM == 128
constexpr int T    = Bc * Nn;      // 36000 total nodes
constexpr int TE   = Bc * Ec;      // 576000 total edges
constexpr float EPS = 1e-5f;

// Scan geometry
constexpr int SCAN_ELEMS = 512;                                // per block
constexpr int NB_SCAN    = (T + SCAN_ELEMS - 1) / SCAN_ELEMS;  // 71

// Workspace layout (bytes). deg/cnt/cur contiguous -> single memset.
constexpr size_t WS_DEG    = 0;          // T f32  (deg -> dinv in place)
constexpr size_t WS_CNT    = 147456;     // T i32
constexpr size_t WS_CUR    = 294912;     // T i32  (fill cursors)
constexpr size_t WS_ROWPTR = 442368;     // T+1 i32
constexpr size_t WS_PART   = 590848;     // NB_SCAN i32 (block partials)
constexpr size_t WS_ESRC   = 591872;     // TE i32
constexpr size_t WS_ECOEF  = 2895872;    // TE f32
constexpr size_t WS_H      = 5199872;    // T*D f32 (GEMM output h)
constexpr size_t WS_ZERO_BYTES = 442368; // deg+cnt+cur in one memset

// ---------------------------------------------------------------------------
// GEMM: h[n][o] = sum_k x[n][k] * W[o][k] + b[o]
// ---------------------------------------------------------------------------
__global__ __launch_bounds__(256) void gemm_kernel(
    const float* __restrict__ x, const float* __restrict__ W,
    const float* __restrict__ bias, float* __restrict__ h) {
  __shared__ float4 Wl[128 * 32];   // [o][k4]
  __shared__ float4 Xl[64 * 33];    // [n][k4], padded

  const int tid = threadIdx.x;
  const int nb  = blockIdx.x * 64;

  const float4* W4 = (const float4*)W;
#pragma unroll
  for (int i = 0; i < 16; ++i) Wl[tid + i * 256] = W4[tid + i * 256];

  const float4* X4 = (const float4*)x;
#pragma unroll
  for (int i = 0; i < 8; ++i) {
    int flat = tid + i * 256;
    int row  = flat >> 5;
    int c4   = flat & 31;
    int node = nb + row;
    float4 v = make_float4(0.f, 0.f, 0.f, 0.f);
    if (node < T) v = X4[node * 32 + c4];
    Xl[row * 33 + c4] = v;
  }
  __syncthreads();

  const int nl = tid & 31;
  const int og = tid >> 5;
  const int o0 = og * 16;

  float accA[16], accB[16];
#pragma unroll
  for (int j = 0; j < 16; ++j) { accA[j] = 0.f; accB[j] = 0.f; }

#pragma unroll 2
  for (int k4 = 0; k4 < 32; ++k4) {
    float4 xa = Xl[nl * 33 + k4];
    float4 xb = Xl[(nl + 32) * 33 + k4];
#pragma unroll
    for (int j = 0; j < 16; ++j) {
      float4 w = Wl[(o0 + j) * 32 + k4];
      accA[j] += xa.x * w.x + xa.y * w.y + xa.z * w.z + xa.w * w.w;
      accB[j] += xb.x * w.x + xb.y * w.y + xb.z * w.z + xb.w * w.w;
    }
  }

  const int nodeA = nb + nl;
  const int nodeB = nb + nl + 32;
  float4* H4 = (float4*)h;
  const float4* B4 = (const float4*)bias;
#pragma unroll
  for (int j4 = 0; j4 < 4; ++j4) {
    float4 bv = B4[og * 4 + j4];
    float4 ra, rb;
    ra.x = accA[j4 * 4 + 0] + bv.x; ra.y = accA[j4 * 4 + 1] + bv.y;
    ra.z = accA[j4 * 4 + 2] + bv.z; ra.w = accA[j4 * 4 + 3] + bv.w;
    rb.x = accB[j4 * 4 + 0] + bv.x; rb.y = accB[j4 * 4 + 1] + bv.y;
    rb.z = accB[j4 * 4 + 2] + bv.z; rb.w = accB[j4 * 4 + 3] + bv.w;
    if (nodeA < T) H4[nodeA * 32 + og * 4 + j4] = ra;
    if (nodeB < T) H4[nodeB * 32 + og * 4 + j4] = rb;
  }
}

// ---------------------------------------------------------------------------
// Edge pass 1: cnt[tgt]++ (all edges) and deg[tgt] += ew (masked).
// ---------------------------------------------------------------------------
__global__ __launch_bounds__(256) void deg_cnt_kernel(
    const int* __restrict__ ei, const float* __restrict__ em,
    float* __restrict__ deg, int* __restrict__ cnt) {
  int e = blockIdx.x * 256 + threadIdx.x;
  if (e >= TE) return;
  int b  = e / Ec;
  int el = e - b * Ec;
  int t = ei[b * 2 * Ec + Ec + el];
  if ((unsigned)t >= (unsigned)Nn) return;   // defensive
  int tg = t + b * Nn;
  atomicAdd(&cnt[tg], 1);
  float ew = em[e];
  if (ew != 0.f) atomicAdd(&deg[tg], ew);
}

// ---------------------------------------------------------------------------
// Scan stage 1: per-block exclusive scan of 512 cnt elements -> rowptr
// (block-local), block total -> partials[bid]. Wave-shuffle based.
// ---------------------------------------------------------------------------
__global__ __launch_bounds__(256) void block_scan_kernel(
    const int* __restrict__ cnt, int* __restrict__ rowptr,
    int* __restrict__ partials) {
  __shared__ int wsum[4];
  const int tid  = threadIdx.x;
  const int base = blockIdx.x * SCAN_ELEMS + tid * 2;

  int a = (base     < T) ? cnt[base]     : 0;
  int b = (base + 1 < T) ? cnt[base + 1] : 0;
  int pair = a + b;

  const int lane = tid & 63;
  const int wid  = tid >> 6;
  int v = pair;
#pragma unroll
  for (int off = 1; off < 64; off <<= 1) {
    int u = __shfl_up(v, off);
    if (lane >= off) v += u;
  }
  if (lane == 63) wsum[wid] = v;
  __syncthreads();

  int woff = 0;
  for (int w = 0; w < wid; ++w) woff += wsum[w];
  const int incl = v + woff;            // inclusive pair-scan within block
  const int excl = incl - pair;         // exclusive at this pair's start

  if (base     < T) rowptr[base]     = excl;
  if (base + 1 < T) rowptr[base + 1] = excl + a;
  if (tid == 255) partials[blockIdx.x] = incl;   // block total
}

// ---------------------------------------------------------------------------
// Scan stage 2: exclusive scan of NB_SCAN block totals (single tiny block).
// Writes rowptr[T] = grand total.
// ---------------------------------------------------------------------------
__global__ __launch_bounds__(128) void partial_scan_kernel(
    int* __restrict__ partials, int* __restrict__ rowptr) {
  __shared__ int sh[128];
  const int i = threadIdx.x;
  int v = (i < NB_SCAN) ? partials[i] : 0;
  sh[i] = v;
  __syncthreads();
#pragma unroll
  for (int off = 1; off < 128; off <<= 1) {
    int u = (i >= off) ? sh[i - off] : 0;
    __syncthreads();
    sh[i] += u;
    __syncthreads();
  }
  if (i < NB_SCAN) partials[i] = sh[i] - v;   // exclusive block offset
  if (i == 127) rowptr[T] = sh[127];
}

// ---------------------------------------------------------------------------
// Scan stage 3: add block offsets; compute dinv = 1/sqrt(deg+1) in place.
// ---------------------------------------------------------------------------
__global__ __launch_bounds__(256) void finalize_kernel(
    int* __restrict__ rowptr, const int* __restrict__ partials,
    float* __restrict__ deg) {
  int i = blockIdx.x * 256 + threadIdx.x;
  if (i >= T) return;
  rowptr[i] += partials[i / SCAN_ELEMS];
  deg[i] = 1.0f / sqrtf(deg[i] + 1.0f);
}

// ---------------------------------------------------------------------------
// Edge pass 2: place each edge into its CSR slot; store src and coef.
// ---------------------------------------------------------------------------
__global__ __launch_bounds__(256) void fill_kernel(
    const int* __restrict__ ei, const float* __restrict__ em,
    const float* __restrict__ dinv, const int* __restrict__ rowptr,
    int* __restrict__ cur, int* __restrict__ esrc,
    float* __restrict__ ecoef) {
  int e = blockIdx.x * 256 + threadIdx.x;
  if (e >= TE) return;
  int b  = e / Ec;
  int el = e - b * Ec;
  const int* eb = ei + b * 2 * Ec;
  int s0 = eb[el];
  int t0 = eb[Ec + el];
  if ((unsigned)s0 >= (unsigned)Nn || (unsigned)t0 >= (unsigned)Nn) return;
  int sg = s0 + b * Nn;
  int tg = t0 + b * Nn;
  float ew   = em[e];
  float coef = dinv[sg] * dinv[tg] * ew;
  int pos = rowptr[tg] + atomicAdd(&cur[tg], 1);
  esrc[pos]  = sg;
  ecoef[pos] = coef;
}

// ---------------------------------------------------------------------------
// Fused gather + residual + LayerNorm + ReLU + mask.
// One 64-lane wave per target node; float2 per lane. No feature atomics.
// ---------------------------------------------------------------------------
__global__ __launch_bounds__(256) void gather_ln_kernel(
    const float* __restrict__ h, const int* __restrict__ rowptr,
    const int* __restrict__ esrc, const float* __restrict__ ecoef,
    const float* __restrict__ dinv, const float* __restrict__ gamma,
    const float* __restrict__ beta, const float* __restrict__ mask,
    float* __restrict__ out) {
  const int node = blockIdx.x * 4 + (threadIdx.x >> 6);
  const int lane = threadIdx.x & 63;
  if (node >= T) return;

  const float2* h2 = (const float2*)h;
  const float di = dinv[node];
  float2 acc = h2[(size_t)node * 64 + lane];
  acc.x *= (1.f + di);
  acc.y *= (1.f + di);

  const int r0 = rowptr[node];
  const int r1 = rowptr[node + 1];
  int i = r0;
  for (; i + 3 < r1; i += 4) {
    int   s0 = esrc[i],     s1 = esrc[i + 1];
    int   s2 = esrc[i + 2], s3 = esrc[i + 3];
    float c0 = ecoef[i],     c1 = ecoef[i + 1];
    float c2 = ecoef[i + 2], c3 = ecoef[i + 3];
    float2 v0 = h2[(size_t)s0 * 64 + lane];
    float2 v1 = h2[(size_t)s1 * 64 + lane];
    float2 v2 = h2[(size_t)s2 * 64 + lane];
    float2 v3 = h2[(size_t)s3 * 64 + lane];
    acc.x += v0.x * c0 + v1.x * c1 + v2.x * c2 + v3.x * c3;
    acc.y += v0.y * c0 + v1.y * c1 + v2.y * c2 + v3.y * c3;
  }
  for (; i < r1; ++i) {
    int   s = esrc[i];
    float c = ecoef[i];
    float2 v = h2[(size_t)s * 64 + lane];
    acc.x += v.x * c;
    acc.y += v.y * c;
  }

  // LayerNorm over 128 features (wave reduction)
  float su = acc.x + acc.y;
  float ss = acc.x * acc.x + acc.y * acc.y;
#pragma unroll
  for (int o = 32; o > 0; o >>= 1) {
    su += __shfl_xor(su, o);
    ss += __shfl_xor(ss, o);
  }
  float mu  = su * (1.0f / 128.0f);
  float var = ss * (1.0f / 128.0f) - mu * mu;
  float rs  = 1.0f / sqrtf(var + EPS);
  float m   = mask[node];

  float2 g  = ((const float2*)gamma)[lane];
  float2 bb = ((const float2*)beta)[lane];
  float y0 = (acc.x - mu) * rs * g.x + bb.x;
  float y1 = (acc.y - mu) * rs * g.y + bb.y;
  y0 = fmaxf(y0, 0.f) * m;
  y1 = fmaxf(y1, 0.f) * m;
  float2 r; r.x = y0; r.y = y1;
  ((float2*)out)[(size_t)node * 64 + lane] = r;
}

// ---------------------------------------------------------------------------
extern "C" void kernel_launch(void* const* d_in, const int* in_sizes, int n_in,
                              void* d_out, int out_size, void* d_ws, size_t ws_size,
                              hipStream_t stream) {
  const float* x     = (const float*)d_in[0];
  const int*   ei    = (const int*)d_in[1];     // int32 on device
  const float* nmask = (const float*)d_in[2];
  const float* emask = (const float*)d_in[3];
  const float* W     = (const float*)d_in[4];
  const float* bias  = (const float*)d_in[5];
  const float* gamma = (const float*)d_in[6];
  const float* beta  = (const float*)d_in[7];
  float* out = (float*)d_out;

  char*  ws     = (char*)d_ws;
  float* deg    = (float*)(ws + WS_DEG);
  int*   cnt    = (int*)  (ws + WS_CNT);
  int*   cur    = (int*)  (ws + WS_CUR);
  int*   rowptr = (int*)  (ws + WS_ROWPTR);
  int*   part   = (int*)  (ws + WS_PART);
  int*   esrc   = (int*)  (ws + WS_ESRC);
  float* ecoef  = (float*)(ws + WS_ECOEF);
  float* h      = (float*)(ws + WS_H);

  // ws is never re-poisoned between replays — zero accumulators every call.
  // deg, cnt, cur are contiguous: one memset.
  hipMemsetAsync(deg, 0, WS_ZERO_BYTES, stream);

  gemm_kernel<<<(T + 63) / 64, 256, 0, stream>>>(x, W, bias, h);
  deg_cnt_kernel<<<(TE + 255) / 256, 256, 0, stream>>>(ei, emask, deg, cnt);
  block_scan_kernel<<<NB_SCAN, 256, 0, stream>>>(cnt, rowptr, part);
  partial_scan_kernel<<<1, 128, 0, stream>>>(part, rowptr);
  finalize_kernel<<<(T + 255) / 256, 256, 0, stream>>>(rowptr, part, deg);
  fill_kernel<<<(TE + 255) / 256, 256, 0, stream>>>(ei, emask, deg, rowptr,
                                                    cur, esrc, ecoef);
  gather_ln_kernel<<<T / 4, 256, 0, stream>>>(h, rowptr, esrc, ecoef, deg,
                                              gamma, beta, nmask, out);
}

// Round 5
// 167.266 us; speedup vs baseline: 6.4675x; 1.1515x over previous
//
#include <hip/hip_runtime.h>
#include <math.h>

typedef unsigned short ushort_t;
typedef unsigned int uint_t;
typedef __attribute__((ext_vector_type(8))) short bf16x8;
typedef __attribute__((ext_vector_type(16))) float f32x16;

// Problem constants (from reference)
constexpr int Bc   = 8;
constexpr int Nn   = 4500;
constexpr int Ec   = 72000;
constexpr int D    = 128;          // IN_DIM == OUT_DIM == 128
constexpr int T    = Bc * Nn;      // 36000 total nodes
constexpr int TE   = Bc * Ec;      // 576000 total edges
constexpr float EPS = 1e-5f;

// Scan geometry
constexpr int SCAN_ELEMS = 512;                                // per block
constexpr int NB_SCAN    = (T + SCAN_ELEMS - 1) / SCAN_ELEMS;  // 71

// Workspace layout (bytes). deg/cnt/cur contiguous -> single memset.
constexpr size_t WS_DEG    = 0;          // T f32  (deg -> dinv in place)
constexpr size_t WS_CNT    = 147456;     // T i32
constexpr size_t WS_CUR    = 294912;     // T i32  (fill cursors)
constexpr size_t WS_ROWPTR = 442368;     // T+1 i32
constexpr size_t WS_PART   = 590848;     // NB_SCAN i32
constexpr size_t WS_ESRC   = 591872;     // TE i32
constexpr size_t WS_ECOEF  = 2895872;    // TE f32
constexpr size_t WS_WHI    = 5199872;    // 128*128 bf16 (32 KB)
constexpr size_t WS_WLO    = 5232640;    // 128*128 bf16 (32 KB)
constexpr size_t WS_H      = 5265408;    // T*D f32 (GEMM output h)
constexpr size_t WS_ZERO_BYTES = 442368; // deg+cnt+cur in one memset

__device__ __forceinline__ ushort_t f32_to_bf16_rne(float f) {
  uint_t u = __float_as_uint(f);
  uint_t r = (u + 0x7fffu + ((u >> 16) & 1u)) >> 16;
  return (ushort_t)r;
}
__device__ __forceinline__ float bf16_to_f32(ushort_t h) {
  return __uint_as_float(((uint_t)h) << 16);
}

// ---------------------------------------------------------------------------
// W prep: split f32 W[o][k] into bf16 hi/lo pair (hi = rne(w), lo = rne(w-hi))
// ---------------------------------------------------------------------------
__global__ __launch_bounds__(256) void wprep_kernel(
    const float* __restrict__ W, ushort_t* __restrict__ Whi,
    ushort_t* __restrict__ Wlo) {
  int i = blockIdx.x * 256 + threadIdx.x;   // 16384 elements
  float w = W[i];
  ushort_t hi = f32_to_bf16_rne(w);
  Whi[i] = hi;
  Wlo[i] = f32_to_bf16_rne(w - bf16_to_f32(hi));
}

// ---------------------------------------------------------------------------
// MFMA GEMM: h[m][o] = sum_k x[m][k]*W[o][k] + b[o], split-bf16 (3 MFMAs).
// One wave per 32 rows; 4 n-tiles of 32 cols; K=128 in 8 steps of 16.
// A/B frag: elem {m,n} = lane&31, k = 8*(lane>>5)+j (j=0..7 contiguous).
// C/D: col = lane&31, row = (reg&3) + 8*(reg>>2) + 4*(lane>>5).
// T % 32 == 0 -> no row tails.
// ---------------------------------------------------------------------------
__global__ __launch_bounds__(256) void gemm_mfma_kernel(
    const float* __restrict__ x, const ushort_t* __restrict__ Whi,
    const ushort_t* __restrict__ Wlo, const float* __restrict__ bias,
    float* __restrict__ h) {
  const int wid  = threadIdx.x >> 6;
  const int lane = threadIdx.x & 63;
  const int m0   = (blockIdx.x * 4 + wid) * 32;
  if (m0 >= T) return;

  const int r  = lane & 31;     // row within A tile / col within B tile
  const int kh = lane >> 5;     // k-half (8 elems)

  const float* xrow = x + (size_t)(m0 + r) * D + kh * 8;

  f32x16 acc[4];
#pragma unroll
  for (int n = 0; n < 4; ++n)
#pragma unroll
    for (int j = 0; j < 16; ++j) acc[n][j] = 0.f;

#pragma unroll 2
  for (int ks = 0; ks < 8; ++ks) {
    const float4 p0 = ((const float4*)(xrow + ks * 16))[0];
    const float4 p1 = ((const float4*)(xrow + ks * 16))[1];
    const float xa[8] = {p0.x, p0.y, p0.z, p0.w, p1.x, p1.y, p1.z, p1.w};
    bf16x8 ahi, alo;
#pragma unroll
    for (int j = 0; j < 8; ++j) {
      ushort_t hb = f32_to_bf16_rne(xa[j]);
      ahi[j] = (short)hb;
      alo[j] = (short)f32_to_bf16_rne(xa[j] - bf16_to_f32(hb));
    }
#pragma unroll
    for (int n = 0; n < 4; ++n) {
      const size_t boff = (size_t)(n * 32 + r) * D + ks * 16 + kh * 8;
      bf16x8 bhi = *(const bf16x8*)(Whi + boff);
      bf16x8 blo = *(const bf16x8*)(Wlo + boff);
      acc[n] = __builtin_amdgcn_mfma_f32_32x32x16_bf16(ahi, bhi, acc[n], 0, 0, 0);
      acc[n] = __builtin_amdgcn_mfma_f32_32x32x16_bf16(ahi, blo, acc[n], 0, 0, 0);
      acc[n] = __builtin_amdgcn_mfma_f32_32x32x16_bf16(alo, bhi, acc[n], 0, 0, 0);
    }
  }

#pragma unroll
  for (int n = 0; n < 4; ++n) {
    const int col = n * 32 + r;
    const float bv = bias[col];
#pragma unroll
    for (int j = 0; j < 16; ++j) {
      const int mrow = m0 + (j & 3) + 8 * (j >> 2) + 4 * kh;
      h[(size_t)mrow * D + col] = acc[n][j] + bv;
    }
  }
}

// ---------------------------------------------------------------------------
// Edge pass 1: cnt[tgt]++ (all edges) and deg[tgt] += ew (masked).
// ---------------------------------------------------------------------------
__global__ __launch_bounds__(256) void deg_cnt_kernel(
    const int* __restrict__ ei, const float* __restrict__ em,
    float* __restrict__ deg, int* __restrict__ cnt) {
  int e = blockIdx.x * 256 + threadIdx.x;
  if (e >= TE) return;
  int b  = e / Ec;
  int el = e - b * Ec;
  int t = ei[b * 2 * Ec + Ec + el];
  if ((unsigned)t >= (unsigned)Nn) return;   // defensive
  int tg = t + b * Nn;
  atomicAdd(&cnt[tg], 1);
  float ew = em[e];
  if (ew != 0.f) atomicAdd(&deg[tg], ew);
}

// ---------------------------------------------------------------------------
// Scan stage 1: per-block exclusive scan of 512 cnt elems -> rowptr,
// block total -> partials[bid].
// ---------------------------------------------------------------------------
__global__ __launch_bounds__(256) void block_scan_kernel(
    const int* __restrict__ cnt, int* __restrict__ rowptr,
    int* __restrict__ partials) {
  __shared__ int wsum[4];
  const int tid  = threadIdx.x;
  const int base = blockIdx.x * SCAN_ELEMS + tid * 2;

  int a = (base     < T) ? cnt[base]     : 0;
  int b = (base + 1 < T) ? cnt[base + 1] : 0;
  int pair = a + b;

  const int lane = tid & 63;
  const int wid  = tid >> 6;
  int v = pair;
#pragma unroll
  for (int off = 1; off < 64; off <<= 1) {
    int u = __shfl_up(v, off);
    if (lane >= off) v += u;
  }
  if (lane == 63) wsum[wid] = v;
  __syncthreads();

  int woff = 0;
  for (int w = 0; w < wid; ++w) woff += wsum[w];
  const int incl = v + woff;
  const int excl = incl - pair;

  if (base     < T) rowptr[base]     = excl;
  if (base + 1 < T) rowptr[base + 1] = excl + a;
  if (tid == 255) partials[blockIdx.x] = incl;
}

// ---------------------------------------------------------------------------
// Scan stage 2: exclusive scan of block totals; rowptr[T] = grand total.
// ---------------------------------------------------------------------------
__global__ __launch_bounds__(128) void partial_scan_kernel(
    int* __restrict__ partials, int* __restrict__ rowptr) {
  __shared__ int sh[128];
  const int i = threadIdx.x;
  int v = (i < NB_SCAN) ? partials[i] : 0;
  sh[i] = v;
  __syncthreads();
#pragma unroll
  for (int off = 1; off < 128; off <<= 1) {
    int u = (i >= off) ? sh[i - off] : 0;
    __syncthreads();
    sh[i] += u;
    __syncthreads();
  }
  if (i < NB_SCAN) partials[i] = sh[i] - v;
  if (i == 127) rowptr[T] = sh[127];
}

// ---------------------------------------------------------------------------
// Scan stage 3: add block offsets; dinv = 1/sqrt(deg+1) in place.
// ---------------------------------------------------------------------------
__global__ __launch_bounds__(256) void finalize_kernel(
    int* __restrict__ rowptr, const int* __restrict__ partials,
    float* __restrict__ deg) {
  int i = blockIdx.x * 256 + threadIdx.x;
  if (i >= T) return;
  rowptr[i] += partials[i / SCAN_ELEMS];
  deg[i] = 1.0f / sqrtf(deg[i] + 1.0f);
}

// ---------------------------------------------------------------------------
// Edge pass 2: place each edge into its CSR slot; store src and coef.
// ---------------------------------------------------------------------------
__global__ __launch_bounds__(256) void fill_kernel(
    const int* __restrict__ ei, const float* __restrict__ em,
    const float* __restrict__ dinv, const int* __restrict__ rowptr,
    int* __restrict__ cur, int* __restrict__ esrc,
    float* __restrict__ ecoef) {
  int e = blockIdx.x * 256 + threadIdx.x;
  if (e >= TE) return;
  int b  = e / Ec;
  int el = e - b * Ec;
  const int* eb = ei + b * 2 * Ec;
  int s0 = eb[el];
  int t0 = eb[Ec + el];
  if ((unsigned)s0 >= (unsigned)Nn || (unsigned)t0 >= (unsigned)Nn) return;
  int sg = s0 + b * Nn;
  int tg = t0 + b * Nn;
  float ew   = em[e];
  float coef = dinv[sg] * dinv[tg] * ew;
  int pos = rowptr[tg] + atomicAdd(&cur[tg], 1);
  esrc[pos]  = sg;
  ecoef[pos] = coef;
}

// ---------------------------------------------------------------------------
// Fused gather + residual + LayerNorm + ReLU + mask.
// One 64-lane wave per target node; float2 per lane. No feature atomics.
// ---------------------------------------------------------------------------
__global__ __launch_bounds__(256) void gather_ln_kernel(
    const float* __restrict__ h, const int* __restrict__ rowptr,
    const int* __restrict__ esrc, const float* __restrict__ ecoef,
    const float* __restrict__ dinv, const float* __restrict__ gamma,
    const float* __restrict__ beta, const float* __restrict__ mask,
    float* __restrict__ out) {
  const int node = blockIdx.x * 4 + (threadIdx.x >> 6);
  const int lane = threadIdx.x & 63;
  if (node >= T) return;

  const float2* h2 = (const float2*)h;
  const float di = dinv[node];
  float2 acc = h2[(size_t)node * 64 + lane];
  acc.x *= (1.f + di);
  acc.y *= (1.f + di);

  const int r0 = rowptr[node];
  const int r1 = rowptr[node + 1];
  int i = r0;
  for (; i + 3 < r1; i += 4) {
    int   s0 = esrc[i],     s1 = esrc[i + 1];
    int   s2 = esrc[i + 2], s3 = esrc[i + 3];
    float c0 = ecoef[i],     c1 = ecoef[i + 1];
    float c2 = ecoef[i + 2], c3 = ecoef[i + 3];
    float2 v0 = h2[(size_t)s0 * 64 + lane];
    float2 v1 = h2[(size_t)s1 * 64 + lane];
    float2 v2 = h2[(size_t)s2 * 64 + lane];
    float2 v3 = h2[(size_t)s3 * 64 + lane];
    acc.x += v0.x * c0 + v1.x * c1 + v2.x * c2 + v3.x * c3;
    acc.y += v0.y * c0 + v1.y * c1 + v2.y * c2 + v3.y * c3;
  }
  for (; i < r1; ++i) {
    int   s = esrc[i];
    float c = ecoef[i];
    float2 v = h2[(size_t)s * 64 + lane];
    acc.x += v.x * c;
    acc.y += v.y * c;
  }

  float su = acc.x + acc.y;
  float ss = acc.x * acc.x + acc.y * acc.y;
#pragma unroll
  for (int o = 32; o > 0; o >>= 1) {
    su += __shfl_xor(su, o);
    ss += __shfl_xor(ss, o);
  }
  float mu  = su * (1.0f / 128.0f);
  float var = ss * (1.0f / 128.0f) - mu * mu;
  float rs  = 1.0f / sqrtf(var + EPS);
  float m   = mask[node];

  float2 g  = ((const float2*)gamma)[lane];
  float2 bb = ((const float2*)beta)[lane];
  float y0 = (acc.x - mu) * rs * g.x + bb.x;
  float y1 = (acc.y - mu) * rs * g.y + bb.y;
  y0 = fmaxf(y0, 0.f) * m;
  y1 = fmaxf(y1, 0.f) * m;
  float2 rv; rv.x = y0; rv.y = y1;
  ((float2*)out)[(size_t)node * 64 + lane] = rv;
}

// ---------------------------------------------------------------------------
extern "C" void kernel_launch(void* const* d_in, const int* in_sizes, int n_in,
                              void* d_out, int out_size, void* d_ws, size_t ws_size,
                              hipStream_t stream) {
  const float* x     = (const float*)d_in[0];
  const int*   ei    = (const int*)d_in[1];     // int32 on device
  const float* nmask = (const float*)d_in[2];
  const float* emask = (const float*)d_in[3];
  const float* W     = (const float*)d_in[4];
  const float* bias  = (const float*)d_in[5];
  const float* gamma = (const float*)d_in[6];
  const float* beta  = (const float*)d_in[7];
  float* out = (float*)d_out;

  char*     ws     = (char*)d_ws;
  float*    deg    = (float*)   (ws + WS_DEG);
  int*      cnt    = (int*)     (ws + WS_CNT);
  int*      cur    = (int*)     (ws + WS_CUR);
  int*      rowptr = (int*)     (ws + WS_ROWPTR);
  int*      part   = (int*)     (ws + WS_PART);
  int*      esrc   = (int*)     (ws + WS_ESRC);
  float*    ecoef  = (float*)   (ws + WS_ECOEF);
  ushort_t* Whi    = (ushort_t*)(ws + WS_WHI);
  ushort_t* Wlo    = (ushort_t*)(ws + WS_WLO);
  float*    h      = (float*)   (ws + WS_H);

  // ws is never re-poisoned between replays — zero accumulators every call.
  hipMemsetAsync(deg, 0, WS_ZERO_BYTES, stream);

  wprep_kernel<<<64, 256, 0, stream>>>(W, Whi, Wlo);
  gemm_mfma_kernel<<<(T / 32 + 3) / 4, 256, 0, stream>>>(x, Whi, Wlo, bias, h);
  deg_cnt_kernel<<<(TE + 255) / 256, 256, 0, stream>>>(ei, emask, deg, cnt);
  block_scan_kernel<<<NB_SCAN, 256, 0, stream>>>(cnt, rowptr, part);
  partial_scan_kernel<<<1, 128, 0, stream>>>(part, rowptr);
  finalize_kernel<<<(T + 255) / 256, 256, 0, stream>>>(rowptr, part, deg);
  fill_kernel<<<(TE + 255) / 256, 256, 0, stream>>>(ei, emask, deg, rowptr,
                                                    cur, esrc, ecoef);
  gather_ln_kernel<<<T / 4, 256, 0, stream>>>(h, rowptr, esrc, ecoef, deg,
                                              gamma, beta, nmask, out);
}

// Round 6
// 129.185 us; speedup vs baseline: 8.3740x; 1.2948x over previous
//
#include <hip/hip_runtime.h>
#include <math.h>

typedef unsigned short ushort_t;
typedef unsigned int uint_t;
typedef __attribute__((ext_vector_type(8))) short bf16x8;
typedef __attribute__((ext_vector_type(16))) float f32x16;

// Problem constants (from reference)
constexpr int Bc   = 8;
constexpr int Nn   = 4500;
constexpr int Ec   = 72000;
constexpr int D    = 128;          // IN_DIM == OUT_DIM == 128
constexpr int T    = Bc * Nn;      // 36000 total nodes
constexpr int TE   = Bc * Ec;      // 576000 total edges
constexpr float EPS = 1e-5f;

// Atomic-counter padding: one counter per 128B line (kills line contention
// at the memory-side cache where device-scope atomics execute).
constexpr int PAD = 32;            // ints per counter slot

// Scan geometry
constexpr int SCAN_ELEMS = 512;                                // per block
constexpr int NB_SCAN    = (T + SCAN_ELEMS - 1) / SCAN_ELEMS;  // 71

// Workspace layout (bytes).
// CNTP (padded counters, 4.6MB) is dead after the scan; EDATA reuses it.
constexpr size_t WS_CNTP   = 0;          // T*PAD i32 = 4,608,000  (-> EDATA)
constexpr size_t WS_EDATA  = 0;          // TE int2  = 4,608,000  (overlay)
constexpr size_t WS_ROWPTR = 4608000;    // (T+1) i32
constexpr size_t WS_PART   = 4752128;    // NB_SCAN i32
constexpr size_t WS_RANK   = 4752640;    // TE i32 = 2,304,000
constexpr size_t WS_DINV   = 7056640;    // T f32
constexpr size_t WS_WHI    = 7200768;    // 128*128 bf16 (32 KB)
constexpr size_t WS_WLO    = 7233536;    // 128*128 bf16 (32 KB)
constexpr size_t WS_H      = 7266304;    // T*D f32 (18.4 MB)

__device__ __forceinline__ ushort_t f32_to_bf16_rne(float f) {
  uint_t u = __float_as_uint(f);
  uint_t r = (u + 0x7fffu + ((u >> 16) & 1u)) >> 16;
  return (ushort_t)r;
}
__device__ __forceinline__ float bf16_to_f32(ushort_t h) {
  return __uint_as_float(((uint_t)h) << 16);
}

// ---------------------------------------------------------------------------
// W prep: split f32 W[o][k] into bf16 hi/lo pair.
// ---------------------------------------------------------------------------
__global__ __launch_bounds__(256) void wprep_kernel(
    const float* __restrict__ W, ushort_t* __restrict__ Whi,
    ushort_t* __restrict__ Wlo) {
  int i = blockIdx.x * 256 + threadIdx.x;   // 16384 elements
  float w = W[i];
  ushort_t hi = f32_to_bf16_rne(w);
  Whi[i] = hi;
  Wlo[i] = f32_to_bf16_rne(w - bf16_to_f32(hi));
}

// ---------------------------------------------------------------------------
// MFMA GEMM: h[m][o] = sum_k x[m][k]*W[o][k] + b[o], split-bf16 (3 MFMAs).
// One wave per 32 rows; 4 n-tiles of 32 cols; K=128 in 8 steps of 16.
// ---------------------------------------------------------------------------
__global__ __launch_bounds__(256) void gemm_mfma_kernel(
    const float* __restrict__ x, const ushort_t* __restrict__ Whi,
    const ushort_t* __restrict__ Wlo, const float* __restrict__ bias,
    float* __restrict__ h) {
  const int wid  = threadIdx.x >> 6;
  const int lane = threadIdx.x & 63;
  const int m0   = (blockIdx.x * 4 + wid) * 32;
  if (m0 >= T) return;

  const int r  = lane & 31;
  const int kh = lane >> 5;

  const float* xrow = x + (size_t)(m0 + r) * D + kh * 8;

  f32x16 acc[4];
#pragma unroll
  for (int n = 0; n < 4; ++n)
#pragma unroll
    for (int j = 0; j < 16; ++j) acc[n][j] = 0.f;

#pragma unroll 2
  for (int ks = 0; ks < 8; ++ks) {
    const float4 p0 = ((const float4*)(xrow + ks * 16))[0];
    const float4 p1 = ((const float4*)(xrow + ks * 16))[1];
    const float xa[8] = {p0.x, p0.y, p0.z, p0.w, p1.x, p1.y, p1.z, p1.w};
    bf16x8 ahi, alo;
#pragma unroll
    for (int j = 0; j < 8; ++j) {
      ushort_t hb = f32_to_bf16_rne(xa[j]);
      ahi[j] = (short)hb;
      alo[j] = (short)f32_to_bf16_rne(xa[j] - bf16_to_f32(hb));
    }
#pragma unroll
    for (int n = 0; n < 4; ++n) {
      const size_t boff = (size_t)(n * 32 + r) * D + ks * 16 + kh * 8;
      bf16x8 bhi = *(const bf16x8*)(Whi + boff);
      bf16x8 blo = *(const bf16x8*)(Wlo + boff);
      acc[n] = __builtin_amdgcn_mfma_f32_32x32x16_bf16(ahi, bhi, acc[n], 0, 0, 0);
      acc[n] = __builtin_amdgcn_mfma_f32_32x32x16_bf16(ahi, blo, acc[n], 0, 0, 0);
      acc[n] = __builtin_amdgcn_mfma_f32_32x32x16_bf16(alo, bhi, acc[n], 0, 0, 0);
    }
  }

#pragma unroll
  for (int n = 0; n < 4; ++n) {
    const int col = n * 32 + r;
    const float bv = bias[col];
#pragma unroll
    for (int j = 0; j < 16; ++j) {
      const int mrow = m0 + (j & 3) + 8 * (j >> 2) + 4 * kh;
      h[(size_t)mrow * D + col] = acc[n][j] + bv;
    }
  }
}

// ---------------------------------------------------------------------------
// Pass 1: rank[e] = fetch-and-add on padded per-target counter.
// Single returning atomic per edge; counter slots 128B apart.
// ---------------------------------------------------------------------------
__global__ __launch_bounds__(256) void rank_kernel(
    const int* __restrict__ ei, int* __restrict__ cntp,
    int* __restrict__ rank) {
  int e = blockIdx.x * 256 + threadIdx.x;
  if (e >= TE) return;
  int b  = e / Ec;
  int el = e - b * Ec;
  int t = ei[b * 2 * Ec + Ec + el];
  if ((unsigned)t >= (unsigned)Nn) { rank[e] = -1; return; }   // defensive
  rank[e] = atomicAdd(&cntp[(size_t)(t + b * Nn) * PAD], 1);
}

// ---------------------------------------------------------------------------
// Scan stage 1: per-block exclusive scan of 512 padded counters -> rowptr,
// block total -> partials[bid].
// ---------------------------------------------------------------------------
__global__ __launch_bounds__(256) void block_scan_kernel(
    const int* __restrict__ cntp, int* __restrict__ rowptr,
    int* __restrict__ partials) {
  __shared__ int wsum[4];
  const int tid  = threadIdx.x;
  const int base = blockIdx.x * SCAN_ELEMS + tid * 2;

  int a = (base     < T) ? cntp[(size_t)base * PAD]       : 0;
  int b = (base + 1 < T) ? cntp[(size_t)(base + 1) * PAD] : 0;
  int pair = a + b;

  const int lane = tid & 63;
  const int wid  = tid >> 6;
  int v = pair;
#pragma unroll
  for (int off = 1; off < 64; off <<= 1) {
    int u = __shfl_up(v, off);
    if (lane >= off) v += u;
  }
  if (lane == 63) wsum[wid] = v;
  __syncthreads();

  int woff = 0;
  for (int w = 0; w < wid; ++w) woff += wsum[w];
  const int incl = v + woff;
  const int excl = incl - pair;

  if (base     < T) rowptr[base]     = excl;
  if (base + 1 < T) rowptr[base + 1] = excl + a;
  if (tid == 255) partials[blockIdx.x] = incl;
}

// ---------------------------------------------------------------------------
// Scan stage 2: exclusive scan of block totals; rowptr[T] = grand total.
// ---------------------------------------------------------------------------
__global__ __launch_bounds__(128) void partial_scan_kernel(
    int* __restrict__ partials, int* __restrict__ rowptr) {
  __shared__ int sh[128];
  const int i = threadIdx.x;
  int v = (i < NB_SCAN) ? partials[i] : 0;
  sh[i] = v;
  __syncthreads();
#pragma unroll
  for (int off = 1; off < 128; off <<= 1) {
    int u = (i >= off) ? sh[i - off] : 0;
    __syncthreads();
    sh[i] += u;
    __syncthreads();
  }
  if (i < NB_SCAN) partials[i] = sh[i] - v;
  if (i == 127) rowptr[T] = sh[127];
}

// ---------------------------------------------------------------------------
// Scan stage 3: add block offsets to rowptr.
// ---------------------------------------------------------------------------
__global__ __launch_bounds__(256) void finalize_kernel(
    int* __restrict__ rowptr, const int* __restrict__ partials) {
  int i = blockIdx.x * 256 + threadIdx.x;
  if (i >= T) return;
  rowptr[i] += partials[i / SCAN_ELEMS];
}

// ---------------------------------------------------------------------------
// Pass 2: place each edge at its deterministic CSR slot (no atomics).
// edata[pos] = {src_global, bits(ew)}.  (edata overlays the dead cntp)
// ---------------------------------------------------------------------------
__global__ __launch_bounds__(256) void fill_kernel(
    const int* __restrict__ ei, const float* __restrict__ em,
    const int* __restrict__ rank, const int* __restrict__ rowptr,
    int2* __restrict__ edata) {
  int e = blockIdx.x * 256 + threadIdx.x;
  if (e >= TE) return;
  int rk = rank[e];
  if (rk < 0) return;
  int b  = e / Ec;
  int el = e - b * Ec;
  const int* eb = ei + b * 2 * Ec;
  int s0 = eb[el];
  int t0 = eb[Ec + el];
  int pos = rowptr[t0 + b * Nn] + rk;
  float ew = em[e];
  int sg;
  if ((unsigned)s0 < (unsigned)Nn) {
    sg = s0 + b * Nn;
  } else {            // defensive: keep slot valid with zero weight
    sg = 0;
    ew = 0.f;
  }
  edata[pos] = make_int2(sg, __float_as_int(ew));
}

// ---------------------------------------------------------------------------
// deg/dinv: per-target streaming sum of ew over its CSR row.
// dinv[t] = 1/sqrt(deg+1).
// ---------------------------------------------------------------------------
__global__ __launch_bounds__(256) void deg_dinv_kernel(
    const int2* __restrict__ edata, const int* __restrict__ rowptr,
    float* __restrict__ dinv) {
  int i = blockIdx.x * 256 + threadIdx.x;
  if (i >= T) return;
  int r0 = rowptr[i], r1 = rowptr[i + 1];
  float s = 0.f;
  for (int j = r0; j < r1; ++j) s += __int_as_float(edata[j].y);
  dinv[i] = 1.0f / sqrtf(s + 1.0f);
}

// ---------------------------------------------------------------------------
// Fused gather + residual + LayerNorm + ReLU + mask.
// result = h[t]*(1+dinv[t]) + dinv[t] * sum_s dinv[s]*ew*h[s]
// One 64-lane wave per target node; float2 per lane.
// ---------------------------------------------------------------------------
__global__ __launch_bounds__(256) void gather_ln_kernel(
    const float* __restrict__ h, const int* __restrict__ rowptr,
    const int2* __restrict__ edata, const float* __restrict__ dinv,
    const float* __restrict__ gamma, const float* __restrict__ beta,
    const float* __restrict__ mask, float* __restrict__ out) {
  const int node = blockIdx.x * 4 + (threadIdx.x >> 6);
  const int lane = threadIdx.x & 63;
  if (node >= T) return;

  const float2* h2 = (const float2*)h;
  const int r0 = rowptr[node];
  const int r1 = rowptr[node + 1];

  float2 accE = make_float2(0.f, 0.f);   // sum of dinv[s]*ew*h[s]
  int i = r0;
  for (; i + 3 < r1; i += 4) {
    int2 e0 = edata[i],     e1 = edata[i + 1];
    int2 e2 = edata[i + 2], e3 = edata[i + 3];
    float c0 = dinv[e0.x] * __int_as_float(e0.y);
    float c1 = dinv[e1.x] * __int_as_float(e1.y);
    float c2 = dinv[e2.x] * __int_as_float(e2.y);
    float c3 = dinv[e3.x] * __int_as_float(e3.y);
    float2 v0 = h2[(size_t)e0.x * 64 + lane];
    float2 v1 = h2[(size_t)e1.x * 64 + lane];
    float2 v2 = h2[(size_t)e2.x * 64 + lane];
    float2 v3 = h2[(size_t)e3.x * 64 + lane];
    accE.x += v0.x * c0 + v1.x * c1 + v2.x * c2 + v3.x * c3;
    accE.y += v0.y * c0 + v1.y * c1 + v2.y * c2 + v3.y * c3;
  }
  for (; i < r1; ++i) {
    int2 e0 = edata[i];
    float c = dinv[e0.x] * __int_as_float(e0.y);
    float2 v = h2[(size_t)e0.x * 64 + lane];
    accE.x += v.x * c;
    accE.y += v.y * c;
  }

  const float dt = dinv[node];
  float2 hv = h2[(size_t)node * 64 + lane];
  float2 acc;
  acc.x = hv.x * (1.f + dt) + dt * accE.x;
  acc.y = hv.y * (1.f + dt) + dt * accE.y;

  float su = acc.x + acc.y;
  float ss = acc.x * acc.x + acc.y * acc.y;
#pragma unroll
  for (int o = 32; o > 0; o >>= 1) {
    su += __shfl_xor(su, o);
    ss += __shfl_xor(ss, o);
  }
  float mu  = su * (1.0f / 128.0f);
  float var = ss * (1.0f / 128.0f) - mu * mu;
  float rs  = 1.0f / sqrtf(var + EPS);
  float m   = mask[node];

  float2 g  = ((const float2*)gamma)[lane];
  float2 bb = ((const float2*)beta)[lane];
  float y0 = (acc.x - mu) * rs * g.x + bb.x;
  float y1 = (acc.y - mu) * rs * g.y + bb.y;
  y0 = fmaxf(y0, 0.f) * m;
  y1 = fmaxf(y1, 0.f) * m;
  float2 rv; rv.x = y0; rv.y = y1;
  ((float2*)out)[(size_t)node * 64 + lane] = rv;
}

// ---------------------------------------------------------------------------
extern "C" void kernel_launch(void* const* d_in, const int* in_sizes, int n_in,
                              void* d_out, int out_size, void* d_ws, size_t ws_size,
                              hipStream_t stream) {
  const float* x     = (const float*)d_in[0];
  const int*   ei    = (const int*)d_in[1];     // int32 on device
  const float* nmask = (const float*)d_in[2];
  const float* emask = (const float*)d_in[3];
  const float* W     = (const float*)d_in[4];
  const float* bias  = (const float*)d_in[5];
  const float* gamma = (const float*)d_in[6];
  const float* beta  = (const float*)d_in[7];
  float* out = (float*)d_out;

  char*     ws     = (char*)d_ws;
  int*      cntp   = (int*)     (ws + WS_CNTP);
  int2*     edata  = (int2*)    (ws + WS_EDATA);   // overlays cntp
  int*      rowptr = (int*)     (ws + WS_ROWPTR);
  int*      part   = (int*)     (ws + WS_PART);
  int*      rank   = (int*)     (ws + WS_RANK);
  float*    dinv   = (float*)   (ws + WS_DINV);
  ushort_t* Whi    = (ushort_t*)(ws + WS_WHI);
  ushort_t* Wlo    = (ushort_t*)(ws + WS_WLO);
  float*    h      = (float*)   (ws + WS_H);

  // ws is never re-poisoned between replays — zero the counters every call.
  hipMemsetAsync(cntp, 0, (size_t)T * PAD * sizeof(int), stream);

  wprep_kernel<<<64, 256, 0, stream>>>(W, Whi, Wlo);
  gemm_mfma_kernel<<<(T / 32 + 3) / 4, 256, 0, stream>>>(x, Whi, Wlo, bias, h);
  rank_kernel<<<(TE + 255) / 256, 256, 0, stream>>>(ei, cntp, rank);
  block_scan_kernel<<<NB_SCAN, 256, 0, stream>>>(cntp, rowptr, part);
  partial_scan_kernel<<<1, 128, 0, stream>>>(part, rowptr);
  finalize_kernel<<<(T + 255) / 256, 256, 0, stream>>>(rowptr, part);
  fill_kernel<<<(TE + 255) / 256, 256, 0, stream>>>(ei, emask, rank, rowptr,
                                                    edata);
  deg_dinv_kernel<<<(T + 255) / 256, 256, 0, stream>>>(edata, rowptr, dinv);
  gather_ln_kernel<<<T / 4, 256, 0, stream>>>(h, rowptr, edata, dinv,
                                              gamma, beta, nmask, out);
}

// Round 7
// 115.579 us; speedup vs baseline: 9.3598x; 1.1177x over previous
//
#include <hip/hip_runtime.h>
#include <math.h>

typedef unsigned short ushort_t;
typedef unsigned int uint_t;
typedef __attribute__((ext_vector_type(8))) short bf16x8;
typedef __attribute__((ext_vector_type(16))) float f32x16;

// Problem constants (from reference)
constexpr int Bc   = 8;
constexpr int Nn   = 4500;
constexpr int Ec   = 72000;
constexpr int D    = 128;          // IN_DIM == OUT_DIM == 128
constexpr int T    = Bc * Nn;      // 36000 total nodes
constexpr int TE   = Bc * Ec;      // 576000 total edges
constexpr float EPS = 1e-5f;

// Atomic-counter padding: one counter per 128B line.
constexpr int PAD = 32;

// Scan geometry
constexpr int SCAN_ELEMS = 512;
constexpr int NB_SCAN    = (T + SCAN_ELEMS - 1) / SCAN_ELEMS;  // 71

// Workspace layout (bytes). EDATA overlays dead CNTP after the scan.
constexpr size_t WS_CNTP   = 0;          // T*PAD i32 = 4,608,000 (-> EDATA)
constexpr size_t WS_EDATA  = 0;          // TE int2  = 4,608,000 (overlay)
constexpr size_t WS_ROWPTR = 4608000;    // (T+1) i32
constexpr size_t WS_PART   = 4752128;    // NB_SCAN i32
constexpr size_t WS_RANK   = 4752640;    // TE i32
constexpr size_t WS_DINV   = 7056640;    // T f32
constexpr size_t WS_WHI    = 7200768;    // 128*128 bf16
constexpr size_t WS_WLO    = 7233536;    // 128*128 bf16
constexpr size_t WS_H      = 7266304;    // T*D f32 (18.4 MB)

__device__ __forceinline__ ushort_t f32_to_bf16_rne(float f) {
  uint_t u = __float_as_uint(f);
  uint_t r = (u + 0x7fffu + ((u >> 16) & 1u)) >> 16;
  return (ushort_t)r;
}
__device__ __forceinline__ float bf16_to_f32(ushort_t h) {
  return __uint_as_float(((uint_t)h) << 16);
}

// ---------------------------------------------------------------------------
// W prep: split f32 W[o][k] into bf16 hi/lo pair.
// ---------------------------------------------------------------------------
__global__ __launch_bounds__(256) void wprep_kernel(
    const float* __restrict__ W, ushort_t* __restrict__ Whi,
    ushort_t* __restrict__ Wlo) {
  int i = blockIdx.x * 256 + threadIdx.x;
  float w = W[i];
  ushort_t hi = f32_to_bf16_rne(w);
  Whi[i] = hi;
  Wlo[i] = f32_to_bf16_rne(w - bf16_to_f32(hi));
}

// ---------------------------------------------------------------------------
// MFMA GEMM: h[m][o] = sum_k x[m][k]*W[o][k] + b[o], split-bf16 (3 MFMAs).
// ---------------------------------------------------------------------------
__global__ __launch_bounds__(256) void gemm_mfma_kernel(
    const float* __restrict__ x, const ushort_t* __restrict__ Whi,
    const ushort_t* __restrict__ Wlo, const float* __restrict__ bias,
    float* __restrict__ h) {
  const int wid  = threadIdx.x >> 6;
  const int lane = threadIdx.x & 63;
  const int m0   = (blockIdx.x * 4 + wid) * 32;
  if (m0 >= T) return;

  const int r  = lane & 31;
  const int kh = lane >> 5;

  const float* xrow = x + (size_t)(m0 + r) * D + kh * 8;

  f32x16 acc[4];
#pragma unroll
  for (int n = 0; n < 4; ++n)
#pragma unroll
    for (int j = 0; j < 16; ++j) acc[n][j] = 0.f;

#pragma unroll 2
  for (int ks = 0; ks < 8; ++ks) {
    const float4 p0 = ((const float4*)(xrow + ks * 16))[0];
    const float4 p1 = ((const float4*)(xrow + ks * 16))[1];
    const float xa[8] = {p0.x, p0.y, p0.z, p0.w, p1.x, p1.y, p1.z, p1.w};
    bf16x8 ahi, alo;
#pragma unroll
    for (int j = 0; j < 8; ++j) {
      ushort_t hb = f32_to_bf16_rne(xa[j]);
      ahi[j] = (short)hb;
      alo[j] = (short)f32_to_bf16_rne(xa[j] - bf16_to_f32(hb));
    }
#pragma unroll
    for (int n = 0; n < 4; ++n) {
      const size_t boff = (size_t)(n * 32 + r) * D + ks * 16 + kh * 8;
      bf16x8 bhi = *(const bf16x8*)(Whi + boff);
      bf16x8 blo = *(const bf16x8*)(Wlo + boff);
      acc[n] = __builtin_amdgcn_mfma_f32_32x32x16_bf16(ahi, bhi, acc[n], 0, 0, 0);
      acc[n] = __builtin_amdgcn_mfma_f32_32x32x16_bf16(ahi, blo, acc[n], 0, 0, 0);
      acc[n] = __builtin_amdgcn_mfma_f32_32x32x16_bf16(alo, bhi, acc[n], 0, 0, 0);
    }
  }

#pragma unroll
  for (int n = 0; n < 4; ++n) {
    const int col = n * 32 + r;
    const float bv = bias[col];
#pragma unroll
    for (int j = 0; j < 16; ++j) {
      const int mrow = m0 + (j & 3) + 8 * (j >> 2) + 4 * kh;
      h[(size_t)mrow * D + col] = acc[n][j] + bv;
    }
  }
}

// ---------------------------------------------------------------------------
// Pass 1: rank[e] = fetch-and-add on padded per-target counter.
// ---------------------------------------------------------------------------
__global__ __launch_bounds__(256) void rank_kernel(
    const int* __restrict__ ei, int* __restrict__ cntp,
    int* __restrict__ rank) {
  int e = blockIdx.x * 256 + threadIdx.x;
  if (e >= TE) return;
  int b  = e / Ec;
  int el = e - b * Ec;
  int t = ei[b * 2 * Ec + Ec + el];
  if ((unsigned)t >= (unsigned)Nn) { rank[e] = -1; return; }
  rank[e] = atomicAdd(&cntp[(size_t)(t + b * Nn) * PAD], 1);
}

// ---------------------------------------------------------------------------
// Scan stage 1
// ---------------------------------------------------------------------------
__global__ __launch_bounds__(256) void block_scan_kernel(
    const int* __restrict__ cntp, int* __restrict__ rowptr,
    int* __restrict__ partials) {
  __shared__ int wsum[4];
  const int tid  = threadIdx.x;
  const int base = blockIdx.x * SCAN_ELEMS + tid * 2;

  int a = (base     < T) ? cntp[(size_t)base * PAD]       : 0;
  int b = (base + 1 < T) ? cntp[(size_t)(base + 1) * PAD] : 0;
  int pair = a + b;

  const int lane = tid & 63;
  const int wid  = tid >> 6;
  int v = pair;
#pragma unroll
  for (int off = 1; off < 64; off <<= 1) {
    int u = __shfl_up(v, off);
    if (lane >= off) v += u;
  }
  if (lane == 63) wsum[wid] = v;
  __syncthreads();

  int woff = 0;
  for (int w = 0; w < wid; ++w) woff += wsum[w];
  const int incl = v + woff;
  const int excl = incl - pair;

  if (base     < T) rowptr[base]     = excl;
  if (base + 1 < T) rowptr[base + 1] = excl + a;
  if (tid == 255) partials[blockIdx.x] = incl;
}

// ---------------------------------------------------------------------------
// Scan stage 2
// ---------------------------------------------------------------------------
__global__ __launch_bounds__(128) void partial_scan_kernel(
    int* __restrict__ partials, int* __restrict__ rowptr) {
  __shared__ int sh[128];
  const int i = threadIdx.x;
  int v = (i < NB_SCAN) ? partials[i] : 0;
  sh[i] = v;
  __syncthreads();
#pragma unroll
  for (int off = 1; off < 128; off <<= 1) {
    int u = (i >= off) ? sh[i - off] : 0;
    __syncthreads();
    sh[i] += u;
    __syncthreads();
  }
  if (i < NB_SCAN) partials[i] = sh[i] - v;
  if (i == 127) rowptr[T] = sh[127];
}

// ---------------------------------------------------------------------------
// Scan stage 3
// ---------------------------------------------------------------------------
__global__ __launch_bounds__(256) void finalize_kernel(
    int* __restrict__ rowptr, const int* __restrict__ partials) {
  int i = blockIdx.x * 256 + threadIdx.x;
  if (i >= T) return;
  rowptr[i] += partials[i / SCAN_ELEMS];
}

// ---------------------------------------------------------------------------
// Pass 2: deterministic CSR placement (no atomics).
// ---------------------------------------------------------------------------
__global__ __launch_bounds__(256) void fill_kernel(
    const int* __restrict__ ei, const float* __restrict__ em,
    const int* __restrict__ rank, const int* __restrict__ rowptr,
    int2* __restrict__ edata) {
  int e = blockIdx.x * 256 + threadIdx.x;
  if (e >= TE) return;
  int rk = rank[e];
  if (rk < 0) return;
  int b  = e / Ec;
  int el = e - b * Ec;
  const int* eb = ei + b * 2 * Ec;
  int s0 = eb[el];
  int t0 = eb[Ec + el];
  int pos = rowptr[t0 + b * Nn] + rk;
  float ew = em[e];
  int sg;
  if ((unsigned)s0 < (unsigned)Nn) {
    sg = s0 + b * Nn;
  } else {
    sg = 0;
    ew = 0.f;
  }
  edata[pos] = make_int2(sg, __float_as_int(ew));
}

// ---------------------------------------------------------------------------
// deg/dinv: per-target streaming sum of ew over its CSR row.
// ---------------------------------------------------------------------------
__global__ __launch_bounds__(256) void deg_dinv_kernel(
    const int2* __restrict__ edata, const int* __restrict__ rowptr,
    float* __restrict__ dinv) {
  int i = blockIdx.x * 256 + threadIdx.x;
  if (i >= T) return;
  int r0 = rowptr[i], r1 = rowptr[i + 1];
  float s = 0.f;
  for (int j = r0; j < r1; ++j) s += __int_as_float(edata[j].y);
  dinv[i] = 1.0f / sqrtf(s + 1.0f);
}

// ---------------------------------------------------------------------------
// Fused gather + residual + LayerNorm + ReLU + mask.
// XCD-pinned: blocks with bid%8==b handle only batch b (h slice 2.3MB -> L2).
// Wave layout: 32 lanes x float4 cover one 128-f row; lane-half h processes
// CSR slots of parity h; halves fold with shfl_xor(32) before LN.
// ---------------------------------------------------------------------------
__global__ __launch_bounds__(256) void gather_ln_kernel(
    const float* __restrict__ h, const int* __restrict__ rowptr,
    const int2* __restrict__ edata, const float* __restrict__ dinv,
    const float* __restrict__ gamma, const float* __restrict__ beta,
    const float* __restrict__ mask, float* __restrict__ out) {
  const int bid  = blockIdx.x;                  // 9000 = 8 * 1125
  const int wid  = threadIdx.x >> 6;
  const int node = (bid & 7) * Nn + (bid >> 3) * 4 + wid;  // XCD-pinned batch
  const int lane = threadIdx.x & 63;
  const int f4   = lane & 31;                   // float4 slot within row
  const int half = lane >> 5;                   // edge parity

  const float4* h4 = (const float4*)h;
  const int r0 = rowptr[node];
  const int r1 = rowptr[node + 1];

  // self row issued early
  float4 hv = h4[(size_t)node * 32 + f4];

  float4 accE = make_float4(0.f, 0.f, 0.f, 0.f);
  int i = r0 + half;
  // 2x unrolled over this half's slots (stride 2 each)
  for (; i + 2 < r1; i += 4) {
    int2 e0 = edata[i];
    int2 e1 = edata[i + 2];
    float c0 = dinv[e0.x] * __int_as_float(e0.y);
    float c1 = dinv[e1.x] * __int_as_float(e1.y);
    float4 v0 = h4[(size_t)e0.x * 32 + f4];
    float4 v1 = h4[(size_t)e1.x * 32 + f4];
    accE.x += v0.x * c0 + v1.x * c1;
    accE.y += v0.y * c0 + v1.y * c1;
    accE.z += v0.z * c0 + v1.z * c1;
    accE.w += v0.w * c0 + v1.w * c1;
  }
  if (i < r1) {
    int2 e0 = edata[i];
    float c0 = dinv[e0.x] * __int_as_float(e0.y);
    float4 v0 = h4[(size_t)e0.x * 32 + f4];
    accE.x += v0.x * c0;
    accE.y += v0.y * c0;
    accE.z += v0.z * c0;
    accE.w += v0.w * c0;
  }

  // fold halves: both end up with the full edge sum
  accE.x += __shfl_xor(accE.x, 32);
  accE.y += __shfl_xor(accE.y, 32);
  accE.z += __shfl_xor(accE.z, 32);
  accE.w += __shfl_xor(accE.w, 32);

  const float dt = dinv[node];
  float4 acc;
  acc.x = hv.x * (1.f + dt) + dt * accE.x;
  acc.y = hv.y * (1.f + dt) + dt * accE.y;
  acc.z = hv.z * (1.f + dt) + dt * accE.z;
  acc.w = hv.w * (1.f + dt) + dt * accE.w;

  // LN reduction within each 32-lane group (identical in both halves)
  float su = acc.x + acc.y + acc.z + acc.w;
  float ss = acc.x * acc.x + acc.y * acc.y + acc.z * acc.z + acc.w * acc.w;
#pragma unroll
  for (int o = 16; o > 0; o >>= 1) {
    su += __shfl_xor(su, o);
    ss += __shfl_xor(ss, o);
  }
  float mu  = su * (1.0f / 128.0f);
  float var = ss * (1.0f / 128.0f) - mu * mu;
  float rs  = 1.0f / sqrtf(var + EPS);
  float m   = mask[node];

  float4 g  = ((const float4*)gamma)[f4];
  float4 bb = ((const float4*)beta)[f4];
  float4 rv;
  rv.x = fmaxf((acc.x - mu) * rs * g.x + bb.x, 0.f) * m;
  rv.y = fmaxf((acc.y - mu) * rs * g.y + bb.y, 0.f) * m;
  rv.z = fmaxf((acc.z - mu) * rs * g.z + bb.z, 0.f) * m;
  rv.w = fmaxf((acc.w - mu) * rs * g.w + bb.w, 0.f) * m;
  if (half == 0) ((float4*)out)[(size_t)node * 32 + f4] = rv;
}

// ---------------------------------------------------------------------------
extern "C" void kernel_launch(void* const* d_in, const int* in_sizes, int n_in,
                              void* d_out, int out_size, void* d_ws, size_t ws_size,
                              hipStream_t stream) {
  const float* x     = (const float*)d_in[0];
  const int*   ei    = (const int*)d_in[1];
  const float* nmask = (const float*)d_in[2];
  const float* emask = (const float*)d_in[3];
  const float* W     = (const float*)d_in[4];
  const float* bias  = (const float*)d_in[5];
  const float* gamma = (const float*)d_in[6];
  const float* beta  = (const float*)d_in[7];
  float* out = (float*)d_out;

  char*     ws     = (char*)d_ws;
  int*      cntp   = (int*)     (ws + WS_CNTP);
  int2*     edata  = (int2*)    (ws + WS_EDATA);   // overlays cntp
  int*      rowptr = (int*)     (ws + WS_ROWPTR);
  int*      part   = (int*)     (ws + WS_PART);
  int*      rank   = (int*)     (ws + WS_RANK);
  float*    dinv   = (float*)   (ws + WS_DINV);
  ushort_t* Whi    = (ushort_t*)(ws + WS_WHI);
  ushort_t* Wlo    = (ushort_t*)(ws + WS_WLO);
  float*    h      = (float*)   (ws + WS_H);

  // ws is never re-poisoned between replays — zero the counters every call.
  hipMemsetAsync(cntp, 0, (size_t)T * PAD * sizeof(int), stream);

  wprep_kernel<<<64, 256, 0, stream>>>(W, Whi, Wlo);
  gemm_mfma_kernel<<<(T / 32 + 3) / 4, 256, 0, stream>>>(x, Whi, Wlo, bias, h);
  rank_kernel<<<(TE + 255) / 256, 256, 0, stream>>>(ei, cntp, rank);
  block_scan_kernel<<<NB_SCAN, 256, 0, stream>>>(cntp, rowptr, part);
  partial_scan_kernel<<<1, 128, 0, stream>>>(part, rowptr);
  finalize_kernel<<<(T + 255) / 256, 256, 0, stream>>>(rowptr, part);
  fill_kernel<<<(TE + 255) / 256, 256, 0, stream>>>(ei, emask, rank, rowptr,
                                                    edata);
  deg_dinv_kernel<<<(T + 255) / 256, 256, 0, stream>>>(edata, rowptr, dinv);
  gather_ln_kernel<<<T / 4, 256, 0, stream>>>(h, rowptr, edata, dinv,
                                              gamma, beta, nmask, out);
}

// Round 8
// 112.406 us; speedup vs baseline: 9.6240x; 1.0282x over previous
//
#include <hip/hip_runtime.h>
#include <math.h>

typedef unsigned short ushort_t;
typedef unsigned int uint_t;
typedef __attribute__((ext_vector_type(8))) short bf16x8;
typedef __attribute__((ext_vector_type(16))) float f32x16;

// Problem constants (from reference)
constexpr int Bc   = 8;
constexpr int Nn   = 4500;
constexpr int Ec   = 72000;
constexpr int D    = 128;          // IN_DIM == OUT_DIM == 128
constexpr int T    = Bc * Nn;      // 36000 total nodes
constexpr int TE   = Bc * Ec;      // 576000 total edges
constexpr float EPS = 1e-5f;

// Atomic-counter padding: one counter per 128B line.
constexpr int PAD = 32;

// Scan geometry
constexpr int SCAN_ELEMS = 512;
constexpr int NB_SCAN    = (T + SCAN_ELEMS - 1) / SCAN_ELEMS;  // 71

// Prep-kernel geometry: 64 wprep blocks + 1125 zero blocks
constexpr int NB_WPREP = 64;                       // 64*256 = 16384 W elems
constexpr int NB_ZERO  = (T * PAD / 4) / 256;      // 1125 int4-blocks
constexpr int NB_PREP  = NB_WPREP + NB_ZERO;

// Workspace layout (bytes). EDATA overlays dead CNTP after the scan.
constexpr size_t WS_CNTP   = 0;          // T*PAD i32 = 4,608,000 (-> EDATA)
constexpr size_t WS_EDATA  = 0;          // TE int2  = 4,608,000 (overlay)
constexpr size_t WS_ROWPTR = 4608000;    // (T+1) i32
constexpr size_t WS_PART   = 4752128;    // NB_SCAN i32
constexpr size_t WS_RANK   = 4752640;    // TE i32
constexpr size_t WS_DINV   = 7056640;    // T f32
constexpr size_t WS_WHI    = 7200768;    // 128*128 bf16
constexpr size_t WS_WLO    = 7233536;    // 128*128 bf16
constexpr size_t WS_H      = 7266304;    // T*D f32 (18.4 MB)

__device__ __forceinline__ ushort_t f32_to_bf16_rne(float f) {
  uint_t u = __float_as_uint(f);
  uint_t r = (u + 0x7fffu + ((u >> 16) & 1u)) >> 16;
  return (ushort_t)r;
}
__device__ __forceinline__ float bf16_to_f32(ushort_t h) {
  return __uint_as_float(((uint_t)h) << 16);
}

// ---------------------------------------------------------------------------
// Prep: blocks [0,64) split W into bf16 hi/lo; blocks [64,1189) zero cntp
// (one int4 per thread — replaces the 44µs runtime fillBuffer).
// ---------------------------------------------------------------------------
__global__ __launch_bounds__(256) void prep_kernel(
    const float* __restrict__ W, ushort_t* __restrict__ Whi,
    ushort_t* __restrict__ Wlo, int4* __restrict__ cntp4) {
  const int bid = blockIdx.x;
  if (bid < NB_WPREP) {
    int i = bid * 256 + threadIdx.x;
    float w = W[i];
    ushort_t hi = f32_to_bf16_rne(w);
    Whi[i] = hi;
    Wlo[i] = f32_to_bf16_rne(w - bf16_to_f32(hi));
  } else {
    int i = (bid - NB_WPREP) * 256 + threadIdx.x;   // < T*PAD/4
    cntp4[i] = make_int4(0, 0, 0, 0);
  }
}

// ---------------------------------------------------------------------------
// MFMA GEMM: h[m][o] = sum_k x[m][k]*W[o][k] + b[o], split-bf16 (3 MFMAs).
// ---------------------------------------------------------------------------
__global__ __launch_bounds__(256) void gemm_mfma_kernel(
    const float* __restrict__ x, const ushort_t* __restrict__ Whi,
    const ushort_t* __restrict__ Wlo, const float* __restrict__ bias,
    float* __restrict__ h) {
  const int wid  = threadIdx.x >> 6;
  const int lane = threadIdx.x & 63;
  const int m0   = (blockIdx.x * 4 + wid) * 32;
  if (m0 >= T) return;

  const int r  = lane & 31;
  const int kh = lane >> 5;

  const float* xrow = x + (size_t)(m0 + r) * D + kh * 8;

  f32x16 acc[4];
#pragma unroll
  for (int n = 0; n < 4; ++n)
#pragma unroll
    for (int j = 0; j < 16; ++j) acc[n][j] = 0.f;

#pragma unroll 2
  for (int ks = 0; ks < 8; ++ks) {
    const float4 p0 = ((const float4*)(xrow + ks * 16))[0];
    const float4 p1 = ((const float4*)(xrow + ks * 16))[1];
    const float xa[8] = {p0.x, p0.y, p0.z, p0.w, p1.x, p1.y, p1.z, p1.w};
    bf16x8 ahi, alo;
#pragma unroll
    for (int j = 0; j < 8; ++j) {
      ushort_t hb = f32_to_bf16_rne(xa[j]);
      ahi[j] = (short)hb;
      alo[j] = (short)f32_to_bf16_rne(xa[j] - bf16_to_f32(hb));
    }
#pragma unroll
    for (int n = 0; n < 4; ++n) {
      const size_t boff = (size_t)(n * 32 + r) * D + ks * 16 + kh * 8;
      bf16x8 bhi = *(const bf16x8*)(Whi + boff);
      bf16x8 blo = *(const bf16x8*)(Wlo + boff);
      acc[n] = __builtin_amdgcn_mfma_f32_32x32x16_bf16(ahi, bhi, acc[n], 0, 0, 0);
      acc[n] = __builtin_amdgcn_mfma_f32_32x32x16_bf16(ahi, blo, acc[n], 0, 0, 0);
      acc[n] = __builtin_amdgcn_mfma_f32_32x32x16_bf16(alo, bhi, acc[n], 0, 0, 0);
    }
  }

#pragma unroll
  for (int n = 0; n < 4; ++n) {
    const int col = n * 32 + r;
    const float bv = bias[col];
#pragma unroll
    for (int j = 0; j < 16; ++j) {
      const int mrow = m0 + (j & 3) + 8 * (j >> 2) + 4 * kh;
      h[(size_t)mrow * D + col] = acc[n][j] + bv;
    }
  }
}

// ---------------------------------------------------------------------------
// Pass 1: rank[e] = fetch-and-add on padded per-target counter.
// ---------------------------------------------------------------------------
__global__ __launch_bounds__(256) void rank_kernel(
    const int* __restrict__ ei, int* __restrict__ cntp,
    int* __restrict__ rank) {
  int e = blockIdx.x * 256 + threadIdx.x;
  if (e >= TE) return;
  int b  = e / Ec;
  int el = e - b * Ec;
  int t = ei[b * 2 * Ec + Ec + el];
  if ((unsigned)t >= (unsigned)Nn) { rank[e] = -1; return; }
  rank[e] = atomicAdd(&cntp[(size_t)(t + b * Nn) * PAD], 1);
}

// ---------------------------------------------------------------------------
// Scan stage 1
// ---------------------------------------------------------------------------
__global__ __launch_bounds__(256) void block_scan_kernel(
    const int* __restrict__ cntp, int* __restrict__ rowptr,
    int* __restrict__ partials) {
  __shared__ int wsum[4];
  const int tid  = threadIdx.x;
  const int base = blockIdx.x * SCAN_ELEMS + tid * 2;

  int a = (base     < T) ? cntp[(size_t)base * PAD]       : 0;
  int b = (base + 1 < T) ? cntp[(size_t)(base + 1) * PAD] : 0;
  int pair = a + b;

  const int lane = tid & 63;
  const int wid  = tid >> 6;
  int v = pair;
#pragma unroll
  for (int off = 1; off < 64; off <<= 1) {
    int u = __shfl_up(v, off);
    if (lane >= off) v += u;
  }
  if (lane == 63) wsum[wid] = v;
  __syncthreads();

  int woff = 0;
  for (int w = 0; w < wid; ++w) woff += wsum[w];
  const int incl = v + woff;
  const int excl = incl - pair;

  if (base     < T) rowptr[base]     = excl;
  if (base + 1 < T) rowptr[base + 1] = excl + a;
  if (tid == 255) partials[blockIdx.x] = incl;
}

// ---------------------------------------------------------------------------
// Scan stage 2
// ---------------------------------------------------------------------------
__global__ __launch_bounds__(128) void partial_scan_kernel(
    int* __restrict__ partials, int* __restrict__ rowptr) {
  __shared__ int sh[128];
  const int i = threadIdx.x;
  int v = (i < NB_SCAN) ? partials[i] : 0;
  sh[i] = v;
  __syncthreads();
#pragma unroll
  for (int off = 1; off < 128; off <<= 1) {
    int u = (i >= off) ? sh[i - off] : 0;
    __syncthreads();
    sh[i] += u;
    __syncthreads();
  }
  if (i < NB_SCAN) partials[i] = sh[i] - v;
  if (i == 127) rowptr[T] = sh[127];
}

// ---------------------------------------------------------------------------
// Scan stage 3
// ---------------------------------------------------------------------------
__global__ __launch_bounds__(256) void finalize_kernel(
    int* __restrict__ rowptr, const int* __restrict__ partials) {
  int i = blockIdx.x * 256 + threadIdx.x;
  if (i >= T) return;
  rowptr[i] += partials[i / SCAN_ELEMS];
}

// ---------------------------------------------------------------------------
// Pass 2: deterministic CSR placement (no atomics).
// ---------------------------------------------------------------------------
__global__ __launch_bounds__(256) void fill_kernel(
    const int* __restrict__ ei, const float* __restrict__ em,
    const int* __restrict__ rank, const int* __restrict__ rowptr,
    int2* __restrict__ edata) {
  int e = blockIdx.x * 256 + threadIdx.x;
  if (e >= TE) return;
  int rk = rank[e];
  if (rk < 0) return;
  int b  = e / Ec;
  int el = e - b * Ec;
  const int* eb = ei + b * 2 * Ec;
  int s0 = eb[el];
  int t0 = eb[Ec + el];
  int pos = rowptr[t0 + b * Nn] + rk;
  float ew = em[e];
  int sg;
  if ((unsigned)s0 < (unsigned)Nn) {
    sg = s0 + b * Nn;
  } else {
    sg = 0;
    ew = 0.f;
  }
  edata[pos] = make_int2(sg, __float_as_int(ew));
}

// ---------------------------------------------------------------------------
// deg/dinv: per-target streaming sum of ew over its CSR row.
// ---------------------------------------------------------------------------
__global__ __launch_bounds__(256) void deg_dinv_kernel(
    const int2* __restrict__ edata, const int* __restrict__ rowptr,
    float* __restrict__ dinv) {
  int i = blockIdx.x * 256 + threadIdx.x;
  if (i >= T) return;
  int r0 = rowptr[i], r1 = rowptr[i + 1];
  float s = 0.f;
  for (int j = r0; j < r1; ++j) s += __int_as_float(edata[j].y);
  dinv[i] = 1.0f / sqrtf(s + 1.0f);
}

// ---------------------------------------------------------------------------
// Fused gather + residual + LayerNorm + ReLU + mask.
// XCD-pinned: blocks with bid%8==b handle only batch b (h slice 2.3MB -> L2).
// ---------------------------------------------------------------------------
__global__ __launch_bounds__(256) void gather_ln_kernel(
    const float* __restrict__ h, const int* __restrict__ rowptr,
    const int2* __restrict__ edata, const float* __restrict__ dinv,
    const float* __restrict__ gamma, const float* __restrict__ beta,
    const float* __restrict__ mask, float* __restrict__ out) {
  const int bid  = blockIdx.x;                  // 9000 = 8 * 1125
  const int wid  = threadIdx.x >> 6;
  const int node = (bid & 7) * Nn + (bid >> 3) * 4 + wid;  // XCD-pinned batch
  const int lane = threadIdx.x & 63;
  const int f4   = lane & 31;                   // float4 slot within row
  const int half = lane >> 5;                   // edge parity

  const float4* h4 = (const float4*)h;
  const int r0 = rowptr[node];
  const int r1 = rowptr[node + 1];

  float4 hv = h4[(size_t)node * 32 + f4];

  float4 accE = make_float4(0.f, 0.f, 0.f, 0.f);
  int i = r0 + half;
  for (; i + 2 < r1; i += 4) {
    int2 e0 = edata[i];
    int2 e1 = edata[i + 2];
    float c0 = dinv[e0.x] * __int_as_float(e0.y);
    float c1 = dinv[e1.x] * __int_as_float(e1.y);
    float4 v0 = h4[(size_t)e0.x * 32 + f4];
    float4 v1 = h4[(size_t)e1.x * 32 + f4];
    accE.x += v0.x * c0 + v1.x * c1;
    accE.y += v0.y * c0 + v1.y * c1;
    accE.z += v0.z * c0 + v1.z * c1;
    accE.w += v0.w * c0 + v1.w * c1;
  }
  if (i < r1) {
    int2 e0 = edata[i];
    float c0 = dinv[e0.x] * __int_as_float(e0.y);
    float4 v0 = h4[(size_t)e0.x * 32 + f4];
    accE.x += v0.x * c0;
    accE.y += v0.y * c0;
    accE.z += v0.z * c0;
    accE.w += v0.w * c0;
  }

  accE.x += __shfl_xor(accE.x, 32);
  accE.y += __shfl_xor(accE.y, 32);
  accE.z += __shfl_xor(accE.z, 32);
  accE.w += __shfl_xor(accE.w, 32);

  const float dt = dinv[node];
  float4 acc;
  acc.x = hv.x * (1.f + dt) + dt * accE.x;
  acc.y = hv.y * (1.f + dt) + dt * accE.y;
  acc.z = hv.z * (1.f + dt) + dt * accE.z;
  acc.w = hv.w * (1.f + dt) + dt * accE.w;

  float su = acc.x + acc.y + acc.z + acc.w;
  float ss = acc.x * acc.x + acc.y * acc.y + acc.z * acc.z + acc.w * acc.w;
#pragma unroll
  for (int o = 16; o > 0; o >>= 1) {
    su += __shfl_xor(su, o);
    ss += __shfl_xor(ss, o);
  }
  float mu  = su * (1.0f / 128.0f);
  float var = ss * (1.0f / 128.0f) - mu * mu;
  float rs  = 1.0f / sqrtf(var + EPS);
  float m   = mask[node];

  float4 g  = ((const float4*)gamma)[f4];
  float4 bb = ((const float4*)beta)[f4];
  float4 rv;
  rv.x = fmaxf((acc.x - mu) * rs * g.x + bb.x, 0.f) * m;
  rv.y = fmaxf((acc.y - mu) * rs * g.y + bb.y, 0.f) * m;
  rv.z = fmaxf((acc.z - mu) * rs * g.z + bb.z, 0.f) * m;
  rv.w = fmaxf((acc.w - mu) * rs * g.w + bb.w, 0.f) * m;
  if (half == 0) ((float4*)out)[(size_t)node * 32 + f4] = rv;
}

// ---------------------------------------------------------------------------
extern "C" void kernel_launch(void* const* d_in, const int* in_sizes, int n_in,
                              void* d_out, int out_size, void* d_ws, size_t ws_size,
                              hipStream_t stream) {
  const float* x     = (const float*)d_in[0];
  const int*   ei    = (const int*)d_in[1];
  const float* nmask = (const float*)d_in[2];
  const float* emask = (const float*)d_in[3];
  const float* W     = (const float*)d_in[4];
  const float* bias  = (const float*)d_in[5];
  const float* gamma = (const float*)d_in[6];
  const float* beta  = (const float*)d_in[7];
  float* out = (float*)d_out;

  char*     ws     = (char*)d_ws;
  int*      cntp   = (int*)     (ws + WS_CNTP);
  int2*     edata  = (int2*)    (ws + WS_EDATA);   // overlays cntp
  int*      rowptr = (int*)     (ws + WS_ROWPTR);
  int*      part   = (int*)     (ws + WS_PART);
  int*      rank   = (int*)     (ws + WS_RANK);
  float*    dinv   = (float*)   (ws + WS_DINV);
  ushort_t* Whi    = (ushort_t*)(ws + WS_WHI);
  ushort_t* Wlo    = (ushort_t*)(ws + WS_WLO);
  float*    h      = (float*)   (ws + WS_H);

  // prep: W split + cntp zeroing (replaces the 44µs runtime fillBuffer).
  prep_kernel<<<NB_PREP, 256, 0, stream>>>(W, Whi, Wlo, (int4*)cntp);
  gemm_mfma_kernel<<<(T / 32 + 3) / 4, 256, 0, stream>>>(x, Whi, Wlo, bias, h);
  rank_kernel<<<(TE + 255) / 256, 256, 0, stream>>>(ei, cntp, rank);
  block_scan_kernel<<<NB_SCAN, 256, 0, stream>>>(cntp, rowptr, part);
  partial_scan_kernel<<<1, 128, 0, stream>>>(part, rowptr);
  finalize_kernel<<<(T + 255) / 256, 256, 0, stream>>>(rowptr, part);
  fill_kernel<<<(TE + 255) / 256, 256, 0, stream>>>(ei, emask, rank, rowptr,
                                                    edata);
  deg_dinv_kernel<<<(T + 255) / 256, 256, 0, stream>>>(edata, rowptr, dinv);
  gather_ln_kernel<<<T / 4, 256, 0, stream>>>(h, rowptr, edata, dinv,
                                              gamma, beta, nmask, out);
}

// Round 9
// 96.779 us; speedup vs baseline: 11.1780x; 1.1615x over previous
//
#include <hip/hip_runtime.h>
#include <math.h>

typedef unsigned short ushort_t;
typedef unsigned int uint_t;
typedef __attribute__((ext_vector_type(8))) short bf16x8;
typedef __attribute__((ext_vector_type(16))) float f32x16;

// Problem constants (from reference)
constexpr int Bc   = 8;
constexpr int Nn   = 4500;
constexpr int Ec   = 72000;
constexpr int D    = 128;          // IN_DIM == OUT_DIM == 128
constexpr int T    = Bc * Nn;      // 36000 total nodes
constexpr int TE   = Bc * Ec;      // 576000 total edges
constexpr float EPS = 1e-5f;

constexpr int PAD = 32;            // ints per counter slot (128B line)
constexpr int RST = 128;           // edata slots per node (fixed-stride rows)

// Prep zones: W split | cntp zero | x split
constexpr int NB_W    = 64;                    // 16384 W elems / 256
constexpr int NB_Z    = (T * PAD / 4) / 256;   // 1125 (int4 zero)
constexpr int NB_X    = (T * D / 4) / 256;     // 4500 (float4 -> 2x ushort4)
constexpr int NB_PREP = NB_W + NB_Z + NB_X;    // 5689

// Workspace layout (bytes); ws is 256 MiB, we use ~78.5 MB.
constexpr size_t WS_CNTP  = 0;            // T*PAD i32 = 4,608,000
constexpr size_t WS_EDATA = 4608000;      // T*RST int2 = 36,864,000
constexpr size_t WS_DINV  = 41472000;     // T f32 = 144,000
constexpr size_t WS_XHI   = 41616000;     // T*D bf16 = 9,216,000
constexpr size_t WS_XLO   = 50832000;     // T*D bf16 = 9,216,000
constexpr size_t WS_WHI   = 60048000;     // 128*128 bf16 = 32,768
constexpr size_t WS_WLO   = 60080768;     // 128*128 bf16 = 32,768
constexpr size_t WS_H     = 60113536;     // T*D f32 = 18,432,000

__device__ __forceinline__ ushort_t f32_to_bf16_rne(float f) {
  uint_t u = __float_as_uint(f);
  uint_t r = (u + 0x7fffu + ((u >> 16) & 1u)) >> 16;
  return (ushort_t)r;
}
__device__ __forceinline__ float bf16_to_f32(ushort_t h) {
  return __uint_as_float(((uint_t)h) << 16);
}

// ---------------------------------------------------------------------------
// Prep (zoned by blockIdx):
//   [0,64):        W -> bf16 hi/lo
//   [64,1189):     zero cntp (int4)
//   [1189,5689):   x -> planar bf16 hi/lo (removes VALU conversion from GEMM)
// ---------------------------------------------------------------------------
__global__ __launch_bounds__(256) void prep_kernel(
    const float* __restrict__ W, ushort_t* __restrict__ Whi,
    ushort_t* __restrict__ Wlo, int4* __restrict__ cntp4,
    const float* __restrict__ x, ushort_t* __restrict__ xhi,
    ushort_t* __restrict__ xlo) {
  const int bid = blockIdx.x;
  if (bid < NB_W) {
    int i = bid * 256 + threadIdx.x;
    float w = W[i];
    ushort_t hi = f32_to_bf16_rne(w);
    Whi[i] = hi;
    Wlo[i] = f32_to_bf16_rne(w - bf16_to_f32(hi));
  } else if (bid < NB_W + NB_Z) {
    int i = (bid - NB_W) * 256 + threadIdx.x;
    cntp4[i] = make_int4(0, 0, 0, 0);
  } else {
    int i = (bid - NB_W - NB_Z) * 256 + threadIdx.x;   // float4 index
    float4 v = ((const float4*)x)[i];
    ushort4 hi, lo;
    hi.x = f32_to_bf16_rne(v.x); lo.x = f32_to_bf16_rne(v.x - bf16_to_f32(hi.x));
    hi.y = f32_to_bf16_rne(v.y); lo.y = f32_to_bf16_rne(v.y - bf16_to_f32(hi.y));
    hi.z = f32_to_bf16_rne(v.z); lo.z = f32_to_bf16_rne(v.z - bf16_to_f32(hi.z));
    hi.w = f32_to_bf16_rne(v.w); lo.w = f32_to_bf16_rne(v.w - bf16_to_f32(hi.w));
    ((ushort4*)xhi)[i] = hi;
    ((ushort4*)xlo)[i] = lo;
  }
}

// ---------------------------------------------------------------------------
// MFMA GEMM, split-bf16 (3 MFMAs): wave = 32 rows x 64 cols (2 n-tiles).
// 2250 waves -> 563 blocks (2.2/CU) for occupancy. No VALU conversion.
// A/B frag: elem = lane&31, k = 8*(lane>>5)+j. C/D: col=lane&31,
// row = (j&3)+8*(j>>2)+4*(lane>>5).
// ---------------------------------------------------------------------------
__global__ __launch_bounds__(256) void gemm_mfma_kernel(
    const ushort_t* __restrict__ xhi, const ushort_t* __restrict__ xlo,
    const ushort_t* __restrict__ Whi, const ushort_t* __restrict__ Wlo,
    const float* __restrict__ bias, float* __restrict__ h) {
  const int g = blockIdx.x * 4 + (threadIdx.x >> 6);
  if (g >= (T / 32) * 2) return;
  const int lane = threadIdx.x & 63;
  const int mt = g >> 1;          // row-tile
  const int nh = g & 1;           // col-half (64 cols)
  const int m0 = mt * 32;
  const int r  = lane & 31;
  const int kh = lane >> 5;

  const size_t arow = (size_t)(m0 + r) * D + kh * 8;

  f32x16 acc[2];
#pragma unroll
  for (int n = 0; n < 2; ++n)
#pragma unroll
    for (int j = 0; j < 16; ++j) acc[n][j] = 0.f;

#pragma unroll
  for (int ks = 0; ks < 8; ++ks) {
    bf16x8 ahi = *(const bf16x8*)(xhi + arow + ks * 16);
    bf16x8 alo = *(const bf16x8*)(xlo + arow + ks * 16);
#pragma unroll
    for (int n = 0; n < 2; ++n) {
      const size_t boff = (size_t)((nh * 2 + n) * 32 + r) * D + ks * 16 + kh * 8;
      bf16x8 bhi = *(const bf16x8*)(Whi + boff);
      bf16x8 blo = *(const bf16x8*)(Wlo + boff);
      acc[n] = __builtin_amdgcn_mfma_f32_32x32x16_bf16(ahi, bhi, acc[n], 0, 0, 0);
      acc[n] = __builtin_amdgcn_mfma_f32_32x32x16_bf16(ahi, blo, acc[n], 0, 0, 0);
      acc[n] = __builtin_amdgcn_mfma_f32_32x32x16_bf16(alo, bhi, acc[n], 0, 0, 0);
    }
  }

#pragma unroll
  for (int n = 0; n < 2; ++n) {
    const int col = (nh * 2 + n) * 32 + r;
    const float bv = bias[col];
#pragma unroll
    for (int j = 0; j < 16; ++j) {
      const int mrow = m0 + (j & 3) + 8 * (j >> 2) + 4 * kh;
      h[(size_t)mrow * D + col] = acc[n][j] + bv;
    }
  }
}

// ---------------------------------------------------------------------------
// Single edge pass: rk = fetch-add on padded counter; direct fixed-stride
// placement edata[tgt*RST + rk] = {src_global, bits(ew)}. No scan, no fill.
// ---------------------------------------------------------------------------
__global__ __launch_bounds__(256) void edge_kernel(
    const int* __restrict__ ei, const float* __restrict__ em,
    int* __restrict__ cntp, int2* __restrict__ edata) {
  int e = blockIdx.x * 256 + threadIdx.x;
  if (e >= TE) return;
  int b  = e / Ec;
  int el = e - b * Ec;
  const int* eb = ei + b * 2 * Ec;
  int t0 = eb[Ec + el];
  if ((unsigned)t0 >= (unsigned)Nn) return;     // defensive
  int tg = t0 + b * Nn;
  int rk = atomicAdd(&cntp[(size_t)tg * PAD], 1);
  if (rk >= RST) return;                        // defensive (P ~ 0)
  int s0 = eb[el];
  float ew = em[e];
  int sg = s0 + b * Nn;
  if ((unsigned)s0 >= (unsigned)Nn) { sg = 0; ew = 0.f; }
  edata[(size_t)tg * RST + rk] = make_int2(sg, __float_as_int(ew));
}

// ---------------------------------------------------------------------------
// deg/dinv: sum ew over the node's edata row; dinv = 1/sqrt(deg+1).
// ---------------------------------------------------------------------------
__global__ __launch_bounds__(256) void deg_dinv_kernel(
    const int2* __restrict__ edata, const int* __restrict__ cntp,
    float* __restrict__ dinv) {
  int i = blockIdx.x * 256 + threadIdx.x;
  if (i >= T) return;
  int cnt = cntp[(size_t)i * PAD];
  cnt = (cnt > RST) ? RST : cnt;
  const int2* row = edata + (size_t)i * RST;
  float s = 0.f;
  for (int j = 0; j < cnt; ++j) s += __int_as_float(row[j].y);
  dinv[i] = 1.0f / sqrtf(s + 1.0f);
}

// ---------------------------------------------------------------------------
// Fused gather + residual + LayerNorm + ReLU + mask.
// XCD-pinned: bid%8 = batch (2.3MB h slice -> per-XCD L2). 32 lanes x float4
// cover a row; lane-half processes alternating slots; fold via shfl_xor(32).
// 4x unrolled per half for gather ILP.
// ---------------------------------------------------------------------------
__global__ __launch_bounds__(256) void gather_ln_kernel(
    const float* __restrict__ h, const int* __restrict__ cntp,
    const int2* __restrict__ edata, const float* __restrict__ dinv,
    const float* __restrict__ gamma, const float* __restrict__ beta,
    const float* __restrict__ mask, float* __restrict__ out) {
  const int bid  = blockIdx.x;                  // 9000 = 8 * 1125
  const int wid  = threadIdx.x >> 6;
  const int node = (bid & 7) * Nn + (bid >> 3) * 4 + wid;
  const int lane = threadIdx.x & 63;
  const int f4   = lane & 31;
  const int half = lane >> 5;

  const float4* h4 = (const float4*)h;
  int cnt = cntp[(size_t)node * PAD];
  cnt = (cnt > RST) ? RST : cnt;
  const int2* row = edata + (size_t)node * RST;

  float4 hv = h4[(size_t)node * 32 + f4];

  float4 accE = make_float4(0.f, 0.f, 0.f, 0.f);
  int i = half;
  for (; i + 6 < cnt; i += 8) {
    int2 e0 = row[i];
    int2 e1 = row[i + 2];
    int2 e2 = row[i + 4];
    int2 e3 = row[i + 6];
    float c0 = dinv[e0.x] * __int_as_float(e0.y);
    float c1 = dinv[e1.x] * __int_as_float(e1.y);
    float c2 = dinv[e2.x] * __int_as_float(e2.y);
    float c3 = dinv[e3.x] * __int_as_float(e3.y);
    float4 v0 = h4[(size_t)e0.x * 32 + f4];
    float4 v1 = h4[(size_t)e1.x * 32 + f4];
    float4 v2 = h4[(size_t)e2.x * 32 + f4];
    float4 v3 = h4[(size_t)e3.x * 32 + f4];
    accE.x += v0.x * c0 + v1.x * c1 + v2.x * c2 + v3.x * c3;
    accE.y += v0.y * c0 + v1.y * c1 + v2.y * c2 + v3.y * c3;
    accE.z += v0.z * c0 + v1.z * c1 + v2.z * c2 + v3.z * c3;
    accE.w += v0.w * c0 + v1.w * c1 + v2.w * c2 + v3.w * c3;
  }
  for (; i < cnt; i += 2) {
    int2 e0 = row[i];
    float c0 = dinv[e0.x] * __int_as_float(e0.y);
    float4 v0 = h4[(size_t)e0.x * 32 + f4];
    accE.x += v0.x * c0;
    accE.y += v0.y * c0;
    accE.z += v0.z * c0;
    accE.w += v0.w * c0;
  }

  accE.x += __shfl_xor(accE.x, 32);
  accE.y += __shfl_xor(accE.y, 32);
  accE.z += __shfl_xor(accE.z, 32);
  accE.w += __shfl_xor(accE.w, 32);

  const float dt = dinv[node];
  float4 acc;
  acc.x = hv.x * (1.f + dt) + dt * accE.x;
  acc.y = hv.y * (1.f + dt) + dt * accE.y;
  acc.z = hv.z * (1.f + dt) + dt * accE.z;
  acc.w = hv.w * (1.f + dt) + dt * accE.w;

  float su = acc.x + acc.y + acc.z + acc.w;
  float ss = acc.x * acc.x + acc.y * acc.y + acc.z * acc.z + acc.w * acc.w;
#pragma unroll
  for (int o = 16; o > 0; o >>= 1) {
    su += __shfl_xor(su, o);
    ss += __shfl_xor(ss, o);
  }
  float mu  = su * (1.0f / 128.0f);
  float var = ss * (1.0f / 128.0f) - mu * mu;
  float rs  = 1.0f / sqrtf(var + EPS);
  float m   = mask[node];

  float4 g  = ((const float4*)gamma)[f4];
  float4 bb = ((const float4*)beta)[f4];
  float4 rv;
  rv.x = fmaxf((acc.x - mu) * rs * g.x + bb.x, 0.f) * m;
  rv.y = fmaxf((acc.y - mu) * rs * g.y + bb.y, 0.f) * m;
  rv.z = fmaxf((acc.z - mu) * rs * g.z + bb.z, 0.f) * m;
  rv.w = fmaxf((acc.w - mu) * rs * g.w + bb.w, 0.f) * m;
  if (half == 0) ((float4*)out)[(size_t)node * 32 + f4] = rv;
}

// ---------------------------------------------------------------------------
extern "C" void kernel_launch(void* const* d_in, const int* in_sizes, int n_in,
                              void* d_out, int out_size, void* d_ws, size_t ws_size,
                              hipStream_t stream) {
  const float* x     = (const float*)d_in[0];
  const int*   ei    = (const int*)d_in[1];
  const float* nmask = (const float*)d_in[2];
  const float* emask = (const float*)d_in[3];
  const float* W     = (const float*)d_in[4];
  const float* bias  = (const float*)d_in[5];
  const float* gamma = (const float*)d_in[6];
  const float* beta  = (const float*)d_in[7];
  float* out = (float*)d_out;

  char*     ws    = (char*)d_ws;
  int*      cntp  = (int*)     (ws + WS_CNTP);
  int2*     edata = (int2*)    (ws + WS_EDATA);
  float*    dinv  = (float*)   (ws + WS_DINV);
  ushort_t* xhi   = (ushort_t*)(ws + WS_XHI);
  ushort_t* xlo   = (ushort_t*)(ws + WS_XLO);
  ushort_t* Whi   = (ushort_t*)(ws + WS_WHI);
  ushort_t* Wlo   = (ushort_t*)(ws + WS_WLO);
  float*    h     = (float*)   (ws + WS_H);

  prep_kernel<<<NB_PREP, 256, 0, stream>>>(W, Whi, Wlo, (int4*)cntp, x, xhi, xlo);
  gemm_mfma_kernel<<<((T / 32) * 2 + 3) / 4, 256, 0, stream>>>(
      xhi, xlo, Whi, Wlo, bias, h);
  edge_kernel<<<(TE + 255) / 256, 256, 0, stream>>>(ei, emask, cntp, edata);
  deg_dinv_kernel<<<(T + 255) / 256, 256, 0, stream>>>(edata, cntp, dinv);
  gather_ln_kernel<<<T / 4, 256, 0, stream>>>(h, cntp, edata, dinv,
                                              gamma, beta, nmask, out);
}